// Round 3
// baseline (1267.322 us; speedup 1.0000x reference)
//
#include <hip/hip_runtime.h>

// SpikingMoEFFN: top-2-of-8 spiking router + per-expert SpikingSwiGLU.
// Grouped-GEMM implementation. Spike decisions emulate the np reference's
// f32 BLAS accumulation: sgemm KC=384 panels, sequential FMA within panel,
// panels added in order (OpenBLAS haswell/zen). bf16x3 MFMA screens the
// |g-1|<1e-3 band; flagged elements re-decided by the exact emulation.

#define D_MODEL 1024
#define HID     2816
#define NEXP    8
#define NTOK    2048
#define NPAIR   4096
#define TM      128
#define MAXTILES 40
#define FLAGCAP  65536
#define KC      384

typedef short s8v __attribute__((ext_vector_type(8)));
typedef float f4v __attribute__((ext_vector_type(4)));

__device__ __forceinline__ unsigned short f2bf(float f) {
  unsigned u = __float_as_uint(f);
  u += 0x7FFFu + ((u >> 16) & 1u);   // RTNE
  return (unsigned short)(u >> 16);
}
__device__ __forceinline__ float bf2f(unsigned short s) {
  return __uint_as_float(((unsigned)s) << 16);
}

// ---------------- x -> bf16 hi/lo split ----------------
__global__ void k_convx(const float* __restrict__ x, unsigned short* __restrict__ xh,
                        unsigned short* __restrict__ xl) {
  const int i = blockIdx.x * 256 + threadIdx.x;
  const float4 v = ((const float4*)x)[i];
  ushort4 h, l;
  h.x = f2bf(v.x); l.x = f2bf(v.x - bf2f(h.x));
  h.y = f2bf(v.y); l.y = f2bf(v.y - bf2f(h.y));
  h.z = f2bf(v.z); l.z = f2bf(v.z - bf2f(h.z));
  h.w = f2bf(v.w); l.w = f2bf(v.w - bf2f(h.w));
  ((ushort4*)xh)[i] = h;
  ((ushort4*)xl)[i] = l;
}

// ------- router: BLAS-emulated f32 logits (KC=384 panels), top-2 spikes -------
__global__ void k_router(const float* __restrict__ x, const float* __restrict__ Wg,
                         const float* __restrict__ bg, int* __restrict__ top_e,
                         float* __restrict__ top_w) {
  const int t = blockIdx.x * blockDim.x + threadIdx.x;
  if (t >= NTOK) return;
  const float* xr = x + (size_t)t * D_MODEL;
  float s[NEXP];
#pragma unroll
  for (int e = 0; e < NEXP; ++e) s[e] = 0.0f;
  for (int p0 = 0; p0 < D_MODEL; p0 += KC) {
    const int pe = min(p0 + KC, D_MODEL);
    float pa[NEXP];
#pragma unroll
    for (int e = 0; e < NEXP; ++e) pa[e] = 0.0f;
    for (int d = p0; d < pe; ++d) {
      const float xv = xr[d];
      const float4 w0 = *(const float4*)(Wg + d * NEXP);
      const float4 w1 = *(const float4*)(Wg + d * NEXP + 4);
      pa[0] = fmaf(xv, w0.x, pa[0]);
      pa[1] = fmaf(xv, w0.y, pa[1]);
      pa[2] = fmaf(xv, w0.z, pa[2]);
      pa[3] = fmaf(xv, w0.w, pa[3]);
      pa[4] = fmaf(xv, w1.x, pa[4]);
      pa[5] = fmaf(xv, w1.y, pa[5]);
      pa[6] = fmaf(xv, w1.z, pa[6]);
      pa[7] = fmaf(xv, w1.w, pa[7]);
    }
#pragma unroll
    for (int e = 0; e < NEXP; ++e) s[e] += pa[e];
  }
  bool sp[NEXP];
#pragma unroll
  for (int e = 0; e < NEXP; ++e) sp[e] = (s[e] + bg[e]) > 1.0f;
  int e0 = -1, e1 = -1;
  for (int e = 0; e < NEXP; ++e) if (sp[e])  { if (e0 < 0) e0 = e; else if (e1 < 0) e1 = e; }
  for (int e = 0; e < NEXP; ++e) if (!sp[e]) { if (e0 < 0) e0 = e; else if (e1 < 0) e1 = e; }
  float w0v, w1v;
  if (sp[e0] == sp[e1]) { w0v = 0.5f; w1v = 0.5f; }
  else { w0v = 0.7310585786300049f; w1v = 0.2689414213699951f; }  // softmax([1,0])
  top_e[2 * t] = e0; top_e[2 * t + 1] = e1;
  top_w[2 * t] = w0v; top_w[2 * t + 1] = w1v;
}

// ---------------- group pairs by expert, build tile table ----------------
__global__ void k_group(const int* __restrict__ top_e,
                        int* __restrict__ pair_token, int* __restrict__ pair_expert,
                        int* __restrict__ tok_pair, int4* __restrict__ tile_tab,
                        int* __restrict__ meta) {
  __shared__ int cnt[NEXP], off[NEXP + 1], fill[NEXP];
  const int tid = threadIdx.x;
  if (tid < NEXP) { cnt[tid] = 0; fill[tid] = 0; }
  __syncthreads();
  for (int i = tid; i < NPAIR; i += 256) atomicAdd(&cnt[top_e[i]], 1);
  __syncthreads();
  if (tid == 0) {
    off[0] = 0;
    for (int e = 0; e < NEXP; ++e) off[e + 1] = off[e] + cnt[e];
    int nt = 0;
    for (int e = 0; e < NEXP; ++e)
      for (int s = 0; s < cnt[e]; s += TM) {
        tile_tab[nt] = make_int4(e, off[e] + s, min(TM, cnt[e] - s), 0);
        ++nt;
      }
    meta[0] = nt;   // ntiles
    meta[1] = 0;    // flag count
  }
  __syncthreads();
  for (int i = tid; i < NPAIR; i += 256) {
    const int e = top_e[i];
    const int pos = off[e] + atomicAdd(&fill[e], 1);
    pair_token[pos] = i >> 1;
    pair_expert[pos] = e;
    tok_pair[i] = pos;
  }
}

// ---------------- stage A: h = spike(x@Wg + bg) * (x@Wu + bu) ----------------
__launch_bounds__(256, 2)
__global__ void k_stage_a(const unsigned short* __restrict__ xh,
                          const unsigned short* __restrict__ xl,
                          const float* __restrict__ Wgate, const float* __restrict__ bgate,
                          const float* __restrict__ Wup, const float* __restrict__ bup,
                          const int* __restrict__ pair_token,
                          const int4* __restrict__ tile_tab,
                          int* meta,
                          unsigned short* __restrict__ hbuf,
                          unsigned int* __restrict__ flags) {
  const int NB = HID / 128;  // 22
  const int tile_id = blockIdx.x / NB;
  const int bn = blockIdx.x % NB;
  if (tile_id >= meta[0]) return;
  const int4 tt = tile_tab[tile_id];
  const int e = tt.x, row0 = tt.y, rows = tt.z;
  const int n0 = bn * 128;

  __shared__ __align__(16) unsigned short la_h[128 * 32];
  __shared__ __align__(16) unsigned short la_l[128 * 32];
  __shared__ __align__(16) unsigned short lb_gh[128 * 32];
  __shared__ __align__(16) unsigned short lb_gl[128 * 32];
  __shared__ __align__(16) unsigned short lb_uh[128 * 32];

  const int tid = threadIdx.x;
  const int lane = tid & 63;
  const int wid = tid >> 6;
  const int wmb = (wid >> 1) * 4;
  const int wnb = (wid & 1) * 4;

  const int amat = tid >> 7;
  const unsigned short* const asrc = amat ? xl : xh;
  unsigned short* const albase = amat ? la_l : la_h;
  const unsigned short* ap[4];
#pragma unroll
  for (int c = 0; c < 4; ++c) {
    const int q = (tid & 127) + 128 * c;
    const int r = ((q >> 6) << 4) + (q & 15);
    const int j = (q & 63) >> 4;
    if (r < rows) {
      const int tok = pair_token[row0 + r];
      ap[c] = asrc + (size_t)tok * D_MODEL + 8 * j;
    } else ap[c] = nullptr;
  }

  const int bsel = tid >> 7;
  const float* const bcolbase = (bsel ? Wup : Wgate) + (size_t)e * D_MODEL * HID + n0;
  const float* bp[4];
  int bj[4];
#pragma unroll
  for (int c = 0; c < 4; ++c) {
    const int q = (tid & 127) + 128 * c;
    const int n = ((q >> 6) << 4) + (q & 15);
    bj[c] = (q & 63) >> 4;
    bp[c] = bcolbase + n;
  }

  const f4v fz = {0.f, 0.f, 0.f, 0.f};
  f4v acc_g[4][4], acc_u[4][4];
#pragma unroll
  for (int m = 0; m < 4; ++m)
#pragma unroll
    for (int n = 0; n < 4; ++n) { acc_g[m][n] = fz; acc_u[m][n] = fz; }

  const s8v sz = {0, 0, 0, 0, 0, 0, 0, 0};

  for (int k0 = 0; k0 < D_MODEL; k0 += 32) {
#pragma unroll
    for (int c = 0; c < 4; ++c) {
      const int q = (tid & 127) + 128 * c;
      s8v v = sz;
      if (ap[c]) v = *(const s8v*)(ap[c] + k0);
      *(s8v*)(albase + q * 8) = v;
    }
    if (bsel == 0) {
#pragma unroll
      for (int c = 0; c < 4; ++c) {
        const int q = (tid & 127) + 128 * c;
        s8v vh, vl;
#pragma unroll
        for (int i = 0; i < 8; ++i) {
          const float g = bp[c][(size_t)(k0 + 8 * bj[c] + i) * HID];
          const unsigned short hh = f2bf(g);
          vh[i] = (short)hh;
          vl[i] = (short)f2bf(g - bf2f(hh));
        }
        *(s8v*)(lb_gh + q * 8) = vh;
        *(s8v*)(lb_gl + q * 8) = vl;
      }
    } else {
#pragma unroll
      for (int c = 0; c < 4; ++c) {
        const int q = (tid & 127) + 128 * c;
        s8v vu;
#pragma unroll
        for (int i = 0; i < 8; ++i)
          vu[i] = (short)f2bf(bp[c][(size_t)(k0 + 8 * bj[c] + i) * HID]);
        *(s8v*)(lb_uh + q * 8) = vu;
      }
    }
    __syncthreads();
    s8v afh[4], afl[4];
#pragma unroll
    for (int m = 0; m < 4; ++m) {
      afh[m] = *(const s8v*)(la_h + ((wmb + m) * 64 + lane) * 8);
      afl[m] = *(const s8v*)(la_l + ((wmb + m) * 64 + lane) * 8);
    }
#pragma unroll
    for (int n = 0; n < 4; ++n) {
      const int boff = ((wnb + n) * 64 + lane) * 8;
      const s8v bgh = *(const s8v*)(lb_gh + boff);
      const s8v bgl = *(const s8v*)(lb_gl + boff);
      const s8v buh = *(const s8v*)(lb_uh + boff);
#pragma unroll
      for (int m = 0; m < 4; ++m) {
        acc_g[m][n] = __builtin_amdgcn_mfma_f32_16x16x32_bf16(afh[m], bgh, acc_g[m][n], 0, 0, 0);
        acc_g[m][n] = __builtin_amdgcn_mfma_f32_16x16x32_bf16(afh[m], bgl, acc_g[m][n], 0, 0, 0);
        acc_g[m][n] = __builtin_amdgcn_mfma_f32_16x16x32_bf16(afl[m], bgh, acc_g[m][n], 0, 0, 0);
        acc_u[m][n] = __builtin_amdgcn_mfma_f32_16x16x32_bf16(afh[m], buh, acc_u[m][n], 0, 0, 0);
      }
    }
    __syncthreads();
  }

  const int lcol = lane & 15;
  const int lrow = (lane >> 4) * 4;
#pragma unroll
  for (int n = 0; n < 4; ++n) {
    const int col = n0 + (wnb + n) * 16 + lcol;
    const float bgv = bgate[e * HID + col];
    const float buv = bup[e * HID + col];
#pragma unroll
    for (int m = 0; m < 4; ++m) {
#pragma unroll
      for (int i = 0; i < 4; ++i) {
        const int r = (wmb + m) * 16 + lrow + i;
        if (r < rows) {
          const float g = acc_g[m][n][i] + bgv;
          const float u = acc_u[m][n][i] + buv;
          hbuf[(size_t)(row0 + r) * HID + col] = f2bf(g > 1.0f ? u : 0.0f);
          if (fabsf(g - 1.0f) < 1e-3f) {
            const unsigned idx = atomicAdd((unsigned*)(meta + 1), 1u);
            if (idx < FLAGCAP) flags[idx] = ((unsigned)(row0 + r) << 16) | (unsigned)col;
          }
        }
      }
    }
  }
}

// ------ patch: re-decide flagged gates via BLAS-emulated f32 (KC=384) ------
__global__ void k_patch(const float* __restrict__ x,
                        const float* __restrict__ Wgate, const float* __restrict__ bgate,
                        const float* __restrict__ Wup, const float* __restrict__ bup,
                        const int* __restrict__ pair_token, const int* __restrict__ pair_expert,
                        const int* __restrict__ meta, const unsigned* __restrict__ flags,
                        unsigned short* __restrict__ hbuf) {
  const int idx = blockIdx.x * blockDim.x + threadIdx.x;
  int n = meta[1];
  if (n > FLAGCAP) n = FLAGCAP;
  if (idx >= n) return;
  const unsigned fl = flags[idx];
  const int row = (int)(fl >> 16);
  const int col = (int)(fl & 0xFFFFu);
  const int tok = pair_token[row];
  const int e = pair_expert[row];
  const float* xr = x + (size_t)tok * D_MODEL;
  const float* wg = Wgate + (size_t)e * D_MODEL * HID + col;
  const float* wu = Wup + (size_t)e * D_MODEL * HID + col;

  // gate: emulate sgemm accumulation — seq FMA within KC=384 panels,
  // panels added to C in order.
  float g = 0.0f;
  for (int p0 = 0; p0 < D_MODEL; p0 += KC) {
    const int pe = min(p0 + KC, D_MODEL);
    float s = 0.0f;
    for (int d = p0; d < pe; ++d)
      s = fmaf(xr[d], wg[(size_t)d * HID], s);
    g += s;
  }
  g += bgate[e * HID + col];
  const bool spike = g > 1.0f;

  // up value: f64 (continuous path, accuracy only)
  double u = 0.0;
  for (int d = 0; d < D_MODEL; ++d)
    u = fma((double)xr[d], (double)wu[(size_t)d * HID], u);
  u += (double)bup[e * HID + col];

  hbuf[(size_t)row * HID + col] = f2bf(spike ? (float)u : 0.0f);
}

// ---------------- stage B: y = h @ W_down ----------------
__launch_bounds__(256, 2)
__global__ void k_stage_b(const unsigned short* __restrict__ hbuf,
                          const float* __restrict__ Wdown,
                          const int4* __restrict__ tile_tab,
                          const int* __restrict__ meta,
                          float* __restrict__ ybuf) {
  const int NB = D_MODEL / 128;  // 8
  const int tile_id = blockIdx.x / NB;
  const int bn = blockIdx.x % NB;
  if (tile_id >= meta[0]) return;
  const int4 tt = tile_tab[tile_id];
  const int e = tt.x, row0 = tt.y, rows = tt.z;
  const int n0 = bn * 128;

  __shared__ __align__(16) unsigned short la[128 * 64];
  __shared__ __align__(16) unsigned short lb[128 * 64];

  const int tid = threadIdx.x;
  const int lane = tid & 63;
  const int wid = tid >> 6;
  const int wmb = (wid >> 1) * 4;
  const int wnb = (wid & 1) * 4;

  const unsigned short* ap[4];
#pragma unroll
  for (int c = 0; c < 4; ++c) {
    const int q = tid + 256 * c;
    const int r = ((q >> 7) << 4) + (q & 15);
    const int j = (q & 127) >> 4;
    ap[c] = (r < rows) ? (hbuf + (size_t)(row0 + r) * HID + 8 * j) : nullptr;
  }
  const float* const bcolbase = Wdown + (size_t)e * HID * D_MODEL + n0;
  const float* bp[4];
  int bj[4];
#pragma unroll
  for (int c = 0; c < 4; ++c) {
    const int q = tid + 256 * c;
    const int n = ((q >> 7) << 4) + (q & 15);
    bj[c] = (q & 127) >> 4;
    bp[c] = bcolbase + n;
  }

  const f4v fz = {0.f, 0.f, 0.f, 0.f};
  f4v acc[4][4];
#pragma unroll
  for (int m = 0; m < 4; ++m)
#pragma unroll
    for (int n = 0; n < 4; ++n) acc[m][n] = fz;
  const s8v sz = {0, 0, 0, 0, 0, 0, 0, 0};

  for (int k0 = 0; k0 < HID; k0 += 64) {
#pragma unroll
    for (int c = 0; c < 4; ++c) {
      const int q = tid + 256 * c;
      s8v v = sz;
      if (ap[c]) v = *(const s8v*)(ap[c] + k0);
      *(s8v*)(la + q * 8) = v;
    }
#pragma unroll
    for (int c = 0; c < 4; ++c) {
      const int q = tid + 256 * c;
      s8v v;
#pragma unroll
      for (int i = 0; i < 8; ++i)
        v[i] = (short)f2bf(bp[c][(size_t)(k0 + 8 * bj[c] + i) * D_MODEL]);
      *(s8v*)(lb + q * 8) = v;
    }
    __syncthreads();
#pragma unroll
    for (int kk = 0; kk < 2; ++kk) {
      s8v af[4];
#pragma unroll
      for (int m = 0; m < 4; ++m)
        af[m] = *(const s8v*)(la + ((wmb + m) * 128 + kk * 64 + lane) * 8);
#pragma unroll
      for (int n = 0; n < 4; ++n) {
        const s8v bv = *(const s8v*)(lb + ((wnb + n) * 128 + kk * 64 + lane) * 8);
#pragma unroll
        for (int m = 0; m < 4; ++m)
          acc[m][n] = __builtin_amdgcn_mfma_f32_16x16x32_bf16(af[m], bv, acc[m][n], 0, 0, 0);
      }
    }
    __syncthreads();
  }

  const int lcol = lane & 15;
  const int lrow = (lane >> 4) * 4;
#pragma unroll
  for (int m = 0; m < 4; ++m)
#pragma unroll
    for (int i = 0; i < 4; ++i) {
      const int r = (wmb + m) * 16 + lrow + i;
      if (r < rows) {
#pragma unroll
        for (int n = 0; n < 4; ++n) {
          const int col = n0 + (wnb + n) * 16 + lcol;
          ybuf[(size_t)(row0 + r) * D_MODEL + col] = acc[m][n][i];
        }
      }
    }
}

// ---------------- combine: out = w0*(y0+bd0) + w1*(y1+bd1) ----------------
__global__ void k_combine(const float* __restrict__ ybuf, const float* __restrict__ bdown,
                          const int* __restrict__ tok_pair, const int* __restrict__ top_e,
                          const float* __restrict__ top_w, float* __restrict__ out) {
  const int t = blockIdx.x;
  const int c = threadIdx.x;
  const int p0 = tok_pair[2 * t], p1 = tok_pair[2 * t + 1];
  const float w0 = top_w[2 * t], w1 = top_w[2 * t + 1];
  const int e0 = top_e[2 * t], e1 = top_e[2 * t + 1];
  const float4 y0 = ((const float4*)(ybuf + (size_t)p0 * D_MODEL))[c];
  const float4 y1 = ((const float4*)(ybuf + (size_t)p1 * D_MODEL))[c];
  const float4 b0 = ((const float4*)(bdown + (size_t)e0 * D_MODEL))[c];
  const float4 b1 = ((const float4*)(bdown + (size_t)e1 * D_MODEL))[c];
  float4 o;
  o.x = w0 * (y0.x + b0.x) + w1 * (y1.x + b1.x);
  o.y = w0 * (y0.y + b0.y) + w1 * (y1.y + b1.y);
  o.z = w0 * (y0.z + b0.z) + w1 * (y1.z + b1.z);
  o.w = w0 * (y0.w + b0.w) + w1 * (y1.w + b1.w);
  ((float4*)(out + (size_t)t * D_MODEL))[c] = o;
}

extern "C" void kernel_launch(void* const* d_in, const int* in_sizes, int n_in,
                              void* d_out, int out_size, void* d_ws, size_t ws_size,
                              hipStream_t stream) {
  const float* x     = (const float*)d_in[0];
  const float* Wg    = (const float*)d_in[1];
  const float* bg    = (const float*)d_in[2];
  const float* Wgate = (const float*)d_in[3];
  const float* bgate = (const float*)d_in[4];
  const float* Wup   = (const float*)d_in[5];
  const float* bup   = (const float*)d_in[6];
  const float* Wdown = (const float*)d_in[7];
  const float* bdown = (const float*)d_in[8];
  float* out = (float*)d_out;

  char* ws = (char*)d_ws;
  unsigned short* xh   = (unsigned short*)(ws + 0);
  unsigned short* xl   = (unsigned short*)(ws + 4194304);
  unsigned short* hbuf = (unsigned short*)(ws + 8388608);
  float* ybuf          = (float*)(ws + 31457280);
  int* top_e           = (int*)(ws + 48234496);
  float* top_w         = (float*)(ws + 48250880);
  int* pair_token      = (int*)(ws + 48267264);
  int* pair_expert     = (int*)(ws + 48283648);
  int* tok_pair        = (int*)(ws + 48300032);
  int4* tile_tab       = (int4*)(ws + 48316416);
  int* meta            = (int*)(ws + 48317184);
  unsigned* flags      = (unsigned*)(ws + 48317440);

  k_convx<<<dim3(NTOK * D_MODEL / 4 / 256), dim3(256), 0, stream>>>(x, xh, xl);
  k_router<<<dim3(NTOK / 256), dim3(256), 0, stream>>>(x, Wg, bg, top_e, top_w);
  k_group<<<dim3(1), dim3(256), 0, stream>>>(top_e, pair_token, pair_expert, tok_pair,
                                             tile_tab, meta);
  k_stage_a<<<dim3(MAXTILES * (HID / 128)), dim3(256), 0, stream>>>(
      xh, xl, Wgate, bgate, Wup, bup, pair_token, tile_tab, meta, hbuf, flags);
  k_patch<<<dim3(FLAGCAP / 256), dim3(256), 0, stream>>>(
      x, Wgate, bgate, Wup, bup, pair_token, pair_expert, meta, flags, hbuf);
  k_stage_b<<<dim3(MAXTILES * (D_MODEL / 128)), dim3(256), 0, stream>>>(
      hbuf, Wdown, tile_tab, meta, ybuf);
  k_combine<<<dim3(NTOK), dim3(256), 0, stream>>>(ybuf, bdown, tok_pair, top_e, top_w, out);
}

// Round 4
// 628.141 us; speedup vs baseline: 2.0176x; 2.0176x over previous
//
#include <hip/hip_runtime.h>

// SpikingMoEFFN: top-2-of-8 spiking router + per-expert SpikingSwiGLU.
// Grouped-GEMM implementation. Spike decisions emulate the np reference's
// f32 BLAS accumulation: sgemm KC=384 panels, sequential FMA within panel,
// panels added in order (verified round 3). bf16x3 MFMA screens the
// |g-1|<3e-4 band; flagged elements re-decided wave-parallel in f64, with
// the exact serial KC=384 emulation only inside |g_f64-1|<2e-5 (20 sigma).

#define D_MODEL 1024
#define HID     2816
#define NEXP    8
#define NTOK    2048
#define NPAIR   4096
#define TM      128
#define MAXTILES 40
#define FLAGCAP  65536
#define KC      384
#define BAND    3e-4f
#define INNER   2e-5

typedef short s8v __attribute__((ext_vector_type(8)));
typedef float f4v __attribute__((ext_vector_type(4)));

__device__ __forceinline__ unsigned short f2bf(float f) {
  unsigned u = __float_as_uint(f);
  u += 0x7FFFu + ((u >> 16) & 1u);   // RTNE
  return (unsigned short)(u >> 16);
}
__device__ __forceinline__ float bf2f(unsigned short s) {
  return __uint_as_float(((unsigned)s) << 16);
}

// Exact np-f32 gate emulation: seq FMA within KC=384 panels, panels added
// in order, then + bias.
__device__ __forceinline__ bool np_spike(const float* __restrict__ xr,
                                         const float* __restrict__ wcol,
                                         size_t stride, float bias) {
  float g = 0.0f;
  for (int p0 = 0; p0 < D_MODEL; p0 += KC) {
    const int pe = min(p0 + KC, D_MODEL);
    float s = 0.0f;
    for (int d = p0; d < pe; ++d)
      s = fmaf(xr[d], wcol[(size_t)d * stride], s);
    g += s;
  }
  g += bias;
  return g > 1.0f;
}

// ---------------- x -> bf16 hi/lo split ----------------
__global__ void k_convx(const float* __restrict__ x, unsigned short* __restrict__ xh,
                        unsigned short* __restrict__ xl) {
  const int i = blockIdx.x * 256 + threadIdx.x;
  const float4 v = ((const float4*)x)[i];
  ushort4 h, l;
  h.x = f2bf(v.x); l.x = f2bf(v.x - bf2f(h.x));
  h.y = f2bf(v.y); l.y = f2bf(v.y - bf2f(h.y));
  h.z = f2bf(v.z); l.z = f2bf(v.z - bf2f(h.z));
  h.w = f2bf(v.w); l.w = f2bf(v.w - bf2f(h.w));
  ((ushort4*)xh)[i] = h;
  ((ushort4*)xl)[i] = l;
}

// ------- router: wave-per-token f64 logits; inner band -> exact np emu -------
__global__ void k_router(const float* __restrict__ x, const float* __restrict__ Wg,
                         const float* __restrict__ bg, int* __restrict__ top_e,
                         float* __restrict__ top_w) {
  const int t = (blockIdx.x * blockDim.x + threadIdx.x) >> 6;
  const int lane = threadIdx.x & 63;
  if (t >= NTOK) return;
  const float* xr = x + (size_t)t * D_MODEL;
  double acc[NEXP];
#pragma unroll
  for (int e = 0; e < NEXP; ++e) acc[e] = 0.0;
#pragma unroll
  for (int i = 0; i < D_MODEL / 64; ++i) {
    const int d = lane + 64 * i;
    const double xv = (double)xr[d];
    const float4 w0 = *(const float4*)(Wg + d * NEXP);
    const float4 w1 = *(const float4*)(Wg + d * NEXP + 4);
    acc[0] = fma(xv, (double)w0.x, acc[0]);
    acc[1] = fma(xv, (double)w0.y, acc[1]);
    acc[2] = fma(xv, (double)w0.z, acc[2]);
    acc[3] = fma(xv, (double)w0.w, acc[3]);
    acc[4] = fma(xv, (double)w1.x, acc[4]);
    acc[5] = fma(xv, (double)w1.y, acc[5]);
    acc[6] = fma(xv, (double)w1.z, acc[6]);
    acc[7] = fma(xv, (double)w1.w, acc[7]);
  }
#pragma unroll
  for (int e = 0; e < NEXP; ++e) {
#pragma unroll
    for (int s = 32; s > 0; s >>= 1) acc[e] += __shfl_down(acc[e], s);
  }
  if (lane == 0) {
    bool sp[NEXP];
#pragma unroll
    for (int e = 0; e < NEXP; ++e) {
      const double l = acc[e] + (double)bg[e];
      if (fabs(l - 1.0) < INNER)
        sp[e] = np_spike(xr, Wg + e, NEXP, bg[e]);
      else
        sp[e] = l > 1.0;
    }
    int e0 = -1, e1 = -1;
    for (int e = 0; e < NEXP; ++e) if (sp[e])  { if (e0 < 0) e0 = e; else if (e1 < 0) e1 = e; }
    for (int e = 0; e < NEXP; ++e) if (!sp[e]) { if (e0 < 0) e0 = e; else if (e1 < 0) e1 = e; }
    float w0v, w1v;
    if (sp[e0] == sp[e1]) { w0v = 0.5f; w1v = 0.5f; }
    else { w0v = 0.7310585786300049f; w1v = 0.2689414213699951f; }  // softmax([1,0])
    top_e[2 * t] = e0; top_e[2 * t + 1] = e1;
    top_w[2 * t] = w0v; top_w[2 * t + 1] = w1v;
  }
}

// ---------------- group pairs by expert, build tile table ----------------
__global__ void k_group(const int* __restrict__ top_e,
                        int* __restrict__ pair_token, int* __restrict__ pair_expert,
                        int* __restrict__ tok_pair, int4* __restrict__ tile_tab,
                        int* __restrict__ meta) {
  __shared__ int cnt[NEXP], off[NEXP + 1], fill[NEXP];
  const int tid = threadIdx.x;
  if (tid < NEXP) { cnt[tid] = 0; fill[tid] = 0; }
  __syncthreads();
  for (int i = tid; i < NPAIR; i += 256) atomicAdd(&cnt[top_e[i]], 1);
  __syncthreads();
  if (tid == 0) {
    off[0] = 0;
    for (int e = 0; e < NEXP; ++e) off[e + 1] = off[e] + cnt[e];
    int nt = 0;
    for (int e = 0; e < NEXP; ++e)
      for (int s = 0; s < cnt[e]; s += TM) {
        tile_tab[nt] = make_int4(e, off[e] + s, min(TM, cnt[e] - s), 0);
        ++nt;
      }
    meta[0] = nt;   // ntiles
    meta[1] = 0;    // flag count
  }
  __syncthreads();
  for (int i = tid; i < NPAIR; i += 256) {
    const int e = top_e[i];
    const int pos = off[e] + atomicAdd(&fill[e], 1);
    pair_token[pos] = i >> 1;
    pair_expert[pos] = e;
    tok_pair[i] = pos;
  }
}

// ---------------- stage A: h = spike(x@Wg + bg) * (x@Wu + bu) ----------------
__launch_bounds__(256, 2)
__global__ void k_stage_a(const unsigned short* __restrict__ xh,
                          const unsigned short* __restrict__ xl,
                          const float* __restrict__ Wgate, const float* __restrict__ bgate,
                          const float* __restrict__ Wup, const float* __restrict__ bup,
                          const int* __restrict__ pair_token,
                          const int4* __restrict__ tile_tab,
                          int* meta,
                          unsigned short* __restrict__ hbuf,
                          unsigned int* __restrict__ flags) {
  const int NB = HID / 128;  // 22
  const int tile_id = blockIdx.x / NB;
  const int bn = blockIdx.x % NB;
  if (tile_id >= meta[0]) return;
  const int4 tt = tile_tab[tile_id];
  const int e = tt.x, row0 = tt.y, rows = tt.z;
  const int n0 = bn * 128;

  __shared__ __align__(16) unsigned short la_h[128 * 32];
  __shared__ __align__(16) unsigned short la_l[128 * 32];
  __shared__ __align__(16) unsigned short lb_gh[128 * 32];
  __shared__ __align__(16) unsigned short lb_gl[128 * 32];
  __shared__ __align__(16) unsigned short lb_uh[128 * 32];

  const int tid = threadIdx.x;
  const int lane = tid & 63;
  const int wid = tid >> 6;
  const int wmb = (wid >> 1) * 4;
  const int wnb = (wid & 1) * 4;

  const int amat = tid >> 7;
  const unsigned short* const asrc = amat ? xl : xh;
  unsigned short* const albase = amat ? la_l : la_h;
  const unsigned short* ap[4];
#pragma unroll
  for (int c = 0; c < 4; ++c) {
    const int q = (tid & 127) + 128 * c;
    const int r = ((q >> 6) << 4) + (q & 15);
    const int j = (q & 63) >> 4;
    if (r < rows) {
      const int tok = pair_token[row0 + r];
      ap[c] = asrc + (size_t)tok * D_MODEL + 8 * j;
    } else ap[c] = nullptr;
  }

  const int bsel = tid >> 7;
  const float* const bcolbase = (bsel ? Wup : Wgate) + (size_t)e * D_MODEL * HID + n0;
  const float* bp[4];
  int bj[4];
#pragma unroll
  for (int c = 0; c < 4; ++c) {
    const int q = (tid & 127) + 128 * c;
    const int n = ((q >> 6) << 4) + (q & 15);
    bj[c] = (q & 63) >> 4;
    bp[c] = bcolbase + n;
  }

  const f4v fz = {0.f, 0.f, 0.f, 0.f};
  f4v acc_g[4][4], acc_u[4][4];
#pragma unroll
  for (int m = 0; m < 4; ++m)
#pragma unroll
    for (int n = 0; n < 4; ++n) { acc_g[m][n] = fz; acc_u[m][n] = fz; }

  const s8v sz = {0, 0, 0, 0, 0, 0, 0, 0};

  for (int k0 = 0; k0 < D_MODEL; k0 += 32) {
#pragma unroll
    for (int c = 0; c < 4; ++c) {
      const int q = (tid & 127) + 128 * c;
      s8v v = sz;
      if (ap[c]) v = *(const s8v*)(ap[c] + k0);
      *(s8v*)(albase + q * 8) = v;
    }
    if (bsel == 0) {
#pragma unroll
      for (int c = 0; c < 4; ++c) {
        const int q = (tid & 127) + 128 * c;
        s8v vh, vl;
#pragma unroll
        for (int i = 0; i < 8; ++i) {
          const float g = bp[c][(size_t)(k0 + 8 * bj[c] + i) * HID];
          const unsigned short hh = f2bf(g);
          vh[i] = (short)hh;
          vl[i] = (short)f2bf(g - bf2f(hh));
        }
        *(s8v*)(lb_gh + q * 8) = vh;
        *(s8v*)(lb_gl + q * 8) = vl;
      }
    } else {
#pragma unroll
      for (int c = 0; c < 4; ++c) {
        const int q = (tid & 127) + 128 * c;
        s8v vu;
#pragma unroll
        for (int i = 0; i < 8; ++i)
          vu[i] = (short)f2bf(bp[c][(size_t)(k0 + 8 * bj[c] + i) * HID]);
        *(s8v*)(lb_uh + q * 8) = vu;
      }
    }
    __syncthreads();
    s8v afh[4], afl[4];
#pragma unroll
    for (int m = 0; m < 4; ++m) {
      afh[m] = *(const s8v*)(la_h + ((wmb + m) * 64 + lane) * 8);
      afl[m] = *(const s8v*)(la_l + ((wmb + m) * 64 + lane) * 8);
    }
#pragma unroll
    for (int n = 0; n < 4; ++n) {
      const int boff = ((wnb + n) * 64 + lane) * 8;
      const s8v bgh = *(const s8v*)(lb_gh + boff);
      const s8v bgl = *(const s8v*)(lb_gl + boff);
      const s8v buh = *(const s8v*)(lb_uh + boff);
#pragma unroll
      for (int m = 0; m < 4; ++m) {
        acc_g[m][n] = __builtin_amdgcn_mfma_f32_16x16x32_bf16(afh[m], bgh, acc_g[m][n], 0, 0, 0);
        acc_g[m][n] = __builtin_amdgcn_mfma_f32_16x16x32_bf16(afh[m], bgl, acc_g[m][n], 0, 0, 0);
        acc_g[m][n] = __builtin_amdgcn_mfma_f32_16x16x32_bf16(afl[m], bgh, acc_g[m][n], 0, 0, 0);
        acc_u[m][n] = __builtin_amdgcn_mfma_f32_16x16x32_bf16(afh[m], buh, acc_u[m][n], 0, 0, 0);
      }
    }
    __syncthreads();
  }

  const int lcol = lane & 15;
  const int lrow = (lane >> 4) * 4;
#pragma unroll
  for (int n = 0; n < 4; ++n) {
    const int col = n0 + (wnb + n) * 16 + lcol;
    const float bgv = bgate[e * HID + col];
    const float buv = bup[e * HID + col];
#pragma unroll
    for (int m = 0; m < 4; ++m) {
#pragma unroll
      for (int i = 0; i < 4; ++i) {
        const int r = (wmb + m) * 16 + lrow + i;
        if (r < rows) {
          const float g = acc_g[m][n][i] + bgv;
          const float u = acc_u[m][n][i] + buv;
          hbuf[(size_t)(row0 + r) * HID + col] = f2bf(g > 1.0f ? u : 0.0f);
          if (fabsf(g - 1.0f) < BAND) {
            const unsigned idx = atomicAdd((unsigned*)(meta + 1), 1u);
            if (idx < FLAGCAP) flags[idx] = ((unsigned)(row0 + r) << 16) | (unsigned)col;
          }
        }
      }
    }
  }
}

// ---- patch: wave-per-flag f64 recompute; inner band -> exact np emulation ----
__global__ void k_patch(const float* __restrict__ x,
                        const float* __restrict__ Wgate, const float* __restrict__ bgate,
                        const float* __restrict__ Wup, const float* __restrict__ bup,
                        const int* __restrict__ pair_token, const int* __restrict__ pair_expert,
                        const int* __restrict__ meta, const unsigned* __restrict__ flags,
                        unsigned short* __restrict__ hbuf) {
  const int nw = (gridDim.x * blockDim.x) >> 6;
  const int w = (blockIdx.x * blockDim.x + threadIdx.x) >> 6;
  const int lane = threadIdx.x & 63;
  int n = meta[1];
  if (n > FLAGCAP) n = FLAGCAP;
  for (int f = w; f < n; f += nw) {
    const unsigned fl = flags[f];
    const int row = (int)(fl >> 16);
    const int col = (int)(fl & 0xFFFFu);
    const int tok = pair_token[row];
    const int e = pair_expert[row];
    const float* xr = x + (size_t)tok * D_MODEL;
    const float* wg = Wgate + (size_t)e * D_MODEL * HID + col;
    const float* wu = Wup + (size_t)e * D_MODEL * HID + col;
    double g = 0.0, u = 0.0;
#pragma unroll
    for (int i = 0; i < D_MODEL / 64; ++i) {
      const int d = lane + 64 * i;
      const double xv = (double)xr[d];
      g = fma(xv, (double)wg[(size_t)d * HID], g);
      u = fma(xv, (double)wu[(size_t)d * HID], u);
    }
#pragma unroll
    for (int s = 32; s > 0; s >>= 1) { g += __shfl_down(g, s); u += __shfl_down(u, s); }
    if (lane == 0) {
      g += (double)bgate[e * HID + col];
      u += (double)bup[e * HID + col];
      bool spike;
      if (fabs(g - 1.0) < INNER)
        spike = np_spike(xr, wg, HID, bgate[e * HID + col]);
      else
        spike = g > 1.0;
      hbuf[(size_t)row * HID + col] = f2bf(spike ? (float)u : 0.0f);
    }
  }
}

// ---------------- stage B: y = h @ W_down ----------------
__launch_bounds__(256, 2)
__global__ void k_stage_b(const unsigned short* __restrict__ hbuf,
                          const float* __restrict__ Wdown,
                          const int4* __restrict__ tile_tab,
                          const int* __restrict__ meta,
                          float* __restrict__ ybuf) {
  const int NB = D_MODEL / 128;  // 8
  const int tile_id = blockIdx.x / NB;
  const int bn = blockIdx.x % NB;
  if (tile_id >= meta[0]) return;
  const int4 tt = tile_tab[tile_id];
  const int e = tt.x, row0 = tt.y, rows = tt.z;
  const int n0 = bn * 128;

  __shared__ __align__(16) unsigned short la[128 * 64];
  __shared__ __align__(16) unsigned short lb[128 * 64];

  const int tid = threadIdx.x;
  const int lane = tid & 63;
  const int wid = tid >> 6;
  const int wmb = (wid >> 1) * 4;
  const int wnb = (wid & 1) * 4;

  const unsigned short* ap[4];
#pragma unroll
  for (int c = 0; c < 4; ++c) {
    const int q = tid + 256 * c;
    const int r = ((q >> 7) << 4) + (q & 15);
    const int j = (q & 127) >> 4;
    ap[c] = (r < rows) ? (hbuf + (size_t)(row0 + r) * HID + 8 * j) : nullptr;
  }
  const float* const bcolbase = Wdown + (size_t)e * HID * D_MODEL + n0;
  const float* bp[4];
  int bj[4];
#pragma unroll
  for (int c = 0; c < 4; ++c) {
    const int q = tid + 256 * c;
    const int n = ((q >> 7) << 4) + (q & 15);
    bj[c] = (q & 127) >> 4;
    bp[c] = bcolbase + n;
  }

  const f4v fz = {0.f, 0.f, 0.f, 0.f};
  f4v acc[4][4];
#pragma unroll
  for (int m = 0; m < 4; ++m)
#pragma unroll
    for (int n = 0; n < 4; ++n) acc[m][n] = fz;
  const s8v sz = {0, 0, 0, 0, 0, 0, 0, 0};

  for (int k0 = 0; k0 < HID; k0 += 64) {
#pragma unroll
    for (int c = 0; c < 4; ++c) {
      const int q = tid + 256 * c;
      s8v v = sz;
      if (ap[c]) v = *(const s8v*)(ap[c] + k0);
      *(s8v*)(la + q * 8) = v;
    }
#pragma unroll
    for (int c = 0; c < 4; ++c) {
      const int q = tid + 256 * c;
      s8v v;
#pragma unroll
      for (int i = 0; i < 8; ++i)
        v[i] = (short)f2bf(bp[c][(size_t)(k0 + 8 * bj[c] + i) * D_MODEL]);
      *(s8v*)(lb + q * 8) = v;
    }
    __syncthreads();
#pragma unroll
    for (int kk = 0; kk < 2; ++kk) {
      s8v af[4];
#pragma unroll
      for (int m = 0; m < 4; ++m)
        af[m] = *(const s8v*)(la + ((wmb + m) * 128 + kk * 64 + lane) * 8);
#pragma unroll
      for (int n = 0; n < 4; ++n) {
        const s8v bv = *(const s8v*)(lb + ((wnb + n) * 128 + kk * 64 + lane) * 8);
#pragma unroll
        for (int m = 0; m < 4; ++m)
          acc[m][n] = __builtin_amdgcn_mfma_f32_16x16x32_bf16(af[m], bv, acc[m][n], 0, 0, 0);
      }
    }
    __syncthreads();
  }

  const int lcol = lane & 15;
  const int lrow = (lane >> 4) * 4;
#pragma unroll
  for (int m = 0; m < 4; ++m)
#pragma unroll
    for (int i = 0; i < 4; ++i) {
      const int r = (wmb + m) * 16 + lrow + i;
      if (r < rows) {
#pragma unroll
        for (int n = 0; n < 4; ++n) {
          const int col = n0 + (wnb + n) * 16 + lcol;
          ybuf[(size_t)(row0 + r) * D_MODEL + col] = acc[m][n][i];
        }
      }
    }
}

// ---------------- combine: out = w0*(y0+bd0) + w1*(y1+bd1) ----------------
__global__ void k_combine(const float* __restrict__ ybuf, const float* __restrict__ bdown,
                          const int* __restrict__ tok_pair, const int* __restrict__ top_e,
                          const float* __restrict__ top_w, float* __restrict__ out) {
  const int t = blockIdx.x;
  const int c = threadIdx.x;
  const int p0 = tok_pair[2 * t], p1 = tok_pair[2 * t + 1];
  const float w0 = top_w[2 * t], w1 = top_w[2 * t + 1];
  const int e0 = top_e[2 * t], e1 = top_e[2 * t + 1];
  const float4 y0 = ((const float4*)(ybuf + (size_t)p0 * D_MODEL))[c];
  const float4 y1 = ((const float4*)(ybuf + (size_t)p1 * D_MODEL))[c];
  const float4 b0 = ((const float4*)(bdown + (size_t)e0 * D_MODEL))[c];
  const float4 b1 = ((const float4*)(bdown + (size_t)e1 * D_MODEL))[c];
  float4 o;
  o.x = w0 * (y0.x + b0.x) + w1 * (y1.x + b1.x);
  o.y = w0 * (y0.y + b0.y) + w1 * (y1.y + b1.y);
  o.z = w0 * (y0.z + b0.z) + w1 * (y1.z + b1.z);
  o.w = w0 * (y0.w + b0.w) + w1 * (y1.w + b1.w);
  ((float4*)(out + (size_t)t * D_MODEL))[c] = o;
}

extern "C" void kernel_launch(void* const* d_in, const int* in_sizes, int n_in,
                              void* d_out, int out_size, void* d_ws, size_t ws_size,
                              hipStream_t stream) {
  const float* x     = (const float*)d_in[0];
  const float* Wg    = (const float*)d_in[1];
  const float* bg    = (const float*)d_in[2];
  const float* Wgate = (const float*)d_in[3];
  const float* bgate = (const float*)d_in[4];
  const float* Wup   = (const float*)d_in[5];
  const float* bup   = (const float*)d_in[6];
  const float* Wdown = (const float*)d_in[7];
  const float* bdown = (const float*)d_in[8];
  float* out = (float*)d_out;

  char* ws = (char*)d_ws;
  unsigned short* xh   = (unsigned short*)(ws + 0);
  unsigned short* xl   = (unsigned short*)(ws + 4194304);
  unsigned short* hbuf = (unsigned short*)(ws + 8388608);
  float* ybuf          = (float*)(ws + 31457280);
  int* top_e           = (int*)(ws + 48234496);
  float* top_w         = (float*)(ws + 48250880);
  int* pair_token      = (int*)(ws + 48267264);
  int* pair_expert     = (int*)(ws + 48283648);
  int* tok_pair        = (int*)(ws + 48300032);
  int4* tile_tab       = (int4*)(ws + 48316416);
  int* meta            = (int*)(ws + 48317184);
  unsigned* flags      = (unsigned*)(ws + 48317440);

  k_convx<<<dim3(NTOK * D_MODEL / 4 / 256), dim3(256), 0, stream>>>(x, xh, xl);
  k_router<<<dim3(NTOK / 4), dim3(256), 0, stream>>>(x, Wg, bg, top_e, top_w);
  k_group<<<dim3(1), dim3(256), 0, stream>>>(top_e, pair_token, pair_expert, tok_pair,
                                             tile_tab, meta);
  k_stage_a<<<dim3(MAXTILES * (HID / 128)), dim3(256), 0, stream>>>(
      xh, xl, Wgate, bgate, Wup, bup, pair_token, tile_tab, meta, hbuf, flags);
  k_patch<<<dim3(512), dim3(256), 0, stream>>>(x, Wgate, bgate, Wup, bup, pair_token,
                                               pair_expert, meta, flags, hbuf);
  k_stage_b<<<dim3(MAXTILES * (D_MODEL / 128)), dim3(256), 0, stream>>>(
      hbuf, Wdown, tile_tab, meta, ybuf);
  k_combine<<<dim3(NTOK), dim3(256), 0, stream>>>(ybuf, bdown, tok_pair, top_e, top_w, out);
}

// Round 5
// 512.077 us; speedup vs baseline: 2.4749x; 1.2267x over previous
//
#include <hip/hip_runtime.h>

// SpikingMoEFFN: top-2-of-8 spiking router + per-expert SpikingSwiGLU.
// Grouped-GEMM implementation. Spike decisions emulate the np reference's
// f32 BLAS accumulation (sgemm KC=384 panels; verified round 3) via bf16x3
// MFMA screen + f64/exact-emulation patch.
// Round 5: pre-convert weights once to TRANSPOSED bf16 panels (Wt[e][n][k],
// k-contiguous) so both GEMM stages do pure 16B bf16 staging with register
// prefetch — no f32 conversion or strided scalar loads in the inner loop.
// Falls back to round-4 on-the-fly-conversion GEMMs if ws_size is too small.

#define D_MODEL 1024
#define HID     2816
#define NEXP    8
#define NTOK    2048
#define NPAIR   4096
#define TM      128
#define MAXTILES 40
#define FLAGCAP  65536
#define KC      384
#define BAND    3e-4f
#define INNER   2e-5

typedef short s8v __attribute__((ext_vector_type(8)));
typedef float f4v __attribute__((ext_vector_type(4)));

__device__ __forceinline__ unsigned short f2bf(float f) {
  unsigned u = __float_as_uint(f);
  u += 0x7FFFu + ((u >> 16) & 1u);   // RTNE
  return (unsigned short)(u >> 16);
}
__device__ __forceinline__ float bf2f(unsigned short s) {
  return __uint_as_float(((unsigned)s) << 16);
}

// Exact np-f32 gate emulation: seq FMA within KC=384 panels, panels added
// in order, then + bias.
__device__ __forceinline__ bool np_spike(const float* __restrict__ xr,
                                         const float* __restrict__ wcol,
                                         size_t stride, float bias) {
  float g = 0.0f;
  for (int p0 = 0; p0 < D_MODEL; p0 += KC) {
    const int pe = min(p0 + KC, D_MODEL);
    float s = 0.0f;
    for (int d = p0; d < pe; ++d)
      s = fmaf(xr[d], wcol[(size_t)d * stride], s);
    g += s;
  }
  g += bias;
  return g > 1.0f;
}

// ---------------- x -> bf16 hi/lo split ----------------
__global__ void k_convx(const float* __restrict__ x, unsigned short* __restrict__ xh,
                        unsigned short* __restrict__ xl) {
  const int i = blockIdx.x * 256 + threadIdx.x;
  const float4 v = ((const float4*)x)[i];
  ushort4 h, l;
  h.x = f2bf(v.x); l.x = f2bf(v.x - bf2f(h.x));
  h.y = f2bf(v.y); l.y = f2bf(v.y - bf2f(h.y));
  h.z = f2bf(v.z); l.z = f2bf(v.z - bf2f(h.z));
  h.w = f2bf(v.w); l.w = f2bf(v.w - bf2f(h.w));
  ((ushort4*)xh)[i] = h;
  ((ushort4*)xl)[i] = l;
}

// ------- weight transpose+convert: in [R][C] f32 -> out [C][R] bf16 (hi[,lo]) ---
__global__ void k_convw(const float* __restrict__ in, unsigned short* __restrict__ hi,
                        unsigned short* __restrict__ lo, int R, int C) {
  const int e = blockIdx.y;
  const int ntx = C >> 6;
  const int tx = blockIdx.x % ntx;
  const int ty = blockIdx.x / ntx;
  const float* src = in + (size_t)e * R * C;
  const size_t obase = (size_t)e * R * C;
  __shared__ float t[64][65];
  const int tid = threadIdx.x;
#pragma unroll
  for (int it = 0; it < 4; ++it) {
    const int r = it * 16 + (tid >> 4);
    const float4 v = *(const float4*)(src + (size_t)(ty * 64 + r) * C + tx * 64 + (tid & 15) * 4);
    t[r][(tid & 15) * 4 + 0] = v.x;
    t[r][(tid & 15) * 4 + 1] = v.y;
    t[r][(tid & 15) * 4 + 2] = v.z;
    t[r][(tid & 15) * 4 + 3] = v.w;
  }
  __syncthreads();
#pragma unroll
  for (int it = 0; it < 2; ++it) {
    const int c = it * 32 + (tid >> 3);
    const int d0 = (tid & 7) * 8;
    s8v vh, vl;
#pragma unroll
    for (int i = 0; i < 8; ++i) {
      const float f = t[d0 + i][c];
      const unsigned short h = f2bf(f);
      vh[i] = (short)h;
      vl[i] = (short)f2bf(f - bf2f(h));
    }
    const size_t o = obase + (size_t)(tx * 64 + c) * R + ty * 64 + d0;
    *(s8v*)(hi + o) = vh;
    if (lo) *(s8v*)(lo + o) = vl;
  }
}

// ------- router: wave-per-token f64 logits; inner band -> exact np emu -------
__global__ void k_router(const float* __restrict__ x, const float* __restrict__ Wg,
                         const float* __restrict__ bg, int* __restrict__ top_e,
                         float* __restrict__ top_w) {
  const int t = (blockIdx.x * blockDim.x + threadIdx.x) >> 6;
  const int lane = threadIdx.x & 63;
  if (t >= NTOK) return;
  const float* xr = x + (size_t)t * D_MODEL;
  double acc[NEXP];
#pragma unroll
  for (int e = 0; e < NEXP; ++e) acc[e] = 0.0;
#pragma unroll
  for (int i = 0; i < D_MODEL / 64; ++i) {
    const int d = lane + 64 * i;
    const double xv = (double)xr[d];
    const float4 w0 = *(const float4*)(Wg + d * NEXP);
    const float4 w1 = *(const float4*)(Wg + d * NEXP + 4);
    acc[0] = fma(xv, (double)w0.x, acc[0]);
    acc[1] = fma(xv, (double)w0.y, acc[1]);
    acc[2] = fma(xv, (double)w0.z, acc[2]);
    acc[3] = fma(xv, (double)w0.w, acc[3]);
    acc[4] = fma(xv, (double)w1.x, acc[4]);
    acc[5] = fma(xv, (double)w1.y, acc[5]);
    acc[6] = fma(xv, (double)w1.z, acc[6]);
    acc[7] = fma(xv, (double)w1.w, acc[7]);
  }
#pragma unroll
  for (int e = 0; e < NEXP; ++e) {
#pragma unroll
    for (int s = 32; s > 0; s >>= 1) acc[e] += __shfl_down(acc[e], s);
  }
  if (lane == 0) {
    bool sp[NEXP];
#pragma unroll
    for (int e = 0; e < NEXP; ++e) {
      const double l = acc[e] + (double)bg[e];
      if (fabs(l - 1.0) < INNER)
        sp[e] = np_spike(xr, Wg + e, NEXP, bg[e]);
      else
        sp[e] = l > 1.0;
    }
    int e0 = -1, e1 = -1;
    for (int e = 0; e < NEXP; ++e) if (sp[e])  { if (e0 < 0) e0 = e; else if (e1 < 0) e1 = e; }
    for (int e = 0; e < NEXP; ++e) if (!sp[e]) { if (e0 < 0) e0 = e; else if (e1 < 0) e1 = e; }
    float w0v, w1v;
    if (sp[e0] == sp[e1]) { w0v = 0.5f; w1v = 0.5f; }
    else { w0v = 0.7310585786300049f; w1v = 0.2689414213699951f; }  // softmax([1,0])
    top_e[2 * t] = e0; top_e[2 * t + 1] = e1;
    top_w[2 * t] = w0v; top_w[2 * t + 1] = w1v;
  }
}

// ---------------- group pairs by expert, build tile table ----------------
__global__ void k_group(const int* __restrict__ top_e,
                        int* __restrict__ pair_token, int* __restrict__ pair_expert,
                        int* __restrict__ tok_pair, int4* __restrict__ tile_tab,
                        int* __restrict__ meta) {
  __shared__ int cnt[NEXP], off[NEXP + 1], fill[NEXP];
  const int tid = threadIdx.x;
  if (tid < NEXP) { cnt[tid] = 0; fill[tid] = 0; }
  __syncthreads();
  for (int i = tid; i < NPAIR; i += 256) atomicAdd(&cnt[top_e[i]], 1);
  __syncthreads();
  if (tid == 0) {
    off[0] = 0;
    for (int e = 0; e < NEXP; ++e) off[e + 1] = off[e] + cnt[e];
    int nt = 0;
    for (int e = 0; e < NEXP; ++e)
      for (int s = 0; s < cnt[e]; s += TM) {
        tile_tab[nt] = make_int4(e, off[e] + s, min(TM, cnt[e] - s), 0);
        ++nt;
      }
    meta[0] = nt;   // ntiles
    meta[1] = 0;    // flag count
  }
  __syncthreads();
  for (int i = tid; i < NPAIR; i += 256) {
    const int e = top_e[i];
    const int pos = off[e] + atomicAdd(&fill[e], 1);
    pair_token[pos] = i >> 1;
    pair_expert[pos] = e;
    tok_pair[i] = pos;
  }
}

// ===== stage A (bf16 pre-converted path): h = spike(x@Wg+bg) * (x@Wu+bu) =====
// All operands bf16, k-contiguous. 5 LDS arrays (A_h, A_l, B_gh, B_gl, B_uh),
// fragment-major; 10x 16B loads/thread/K-step with 1-step register prefetch.
__launch_bounds__(256, 2)
__global__ void k_stage_a_bf(const unsigned short* __restrict__ xh,
                             const unsigned short* __restrict__ xl,
                             const unsigned short* __restrict__ wgh,
                             const unsigned short* __restrict__ wgl,
                             const unsigned short* __restrict__ wuh,
                             const float* __restrict__ bgate, const float* __restrict__ bup,
                             const int* __restrict__ pair_token,
                             const int4* __restrict__ tile_tab,
                             int* meta,
                             unsigned short* __restrict__ hbuf,
                             unsigned int* __restrict__ flags) {
  const int NB = HID / 128;  // 22
  const int tile_id = blockIdx.x / NB;
  const int bn = blockIdx.x % NB;
  if (tile_id >= meta[0]) return;
  const int4 tt = tile_tab[tile_id];
  const int e = tt.x, row0 = tt.y, rows = tt.z;
  const int n0 = bn * 128;

  __shared__ __align__(16) unsigned short lds[5 * 4096];

  const int tid = threadIdx.x;
  const int lane = tid & 63;
  const int wid = tid >> 6;
  const int wmb = (wid >> 1) * 4;
  const int wnb = (wid & 1) * 4;

  const unsigned short* p[10];
#pragma unroll
  for (int c = 0; c < 10; ++c) {
    const int idx = tid + 256 * c;
    const int arr = idx >> 9;
    const int q = idx & 511;
    const int rn = ((q >> 6) << 4) + (q & 15);
    const int j = (q & 63) >> 4;
    if (arr < 2) {
      if (rn < rows) {
        const int tok = pair_token[row0 + rn];
        p[c] = (arr ? xl : xh) + (size_t)tok * D_MODEL + 8 * j;
      } else p[c] = nullptr;
    } else {
      const unsigned short* base = (arr == 2) ? wgh : (arr == 3) ? wgl : wuh;
      p[c] = base + ((size_t)e * HID + n0 + rn) * D_MODEL + 8 * j;
    }
  }

  const f4v fz = {0.f, 0.f, 0.f, 0.f};
  f4v acc_g[4][4], acc_u[4][4];
#pragma unroll
  for (int m = 0; m < 4; ++m)
#pragma unroll
    for (int n = 0; n < 4; ++n) { acc_g[m][n] = fz; acc_u[m][n] = fz; }

  const s8v sz = {0, 0, 0, 0, 0, 0, 0, 0};
  s8v v[10];
#pragma unroll
  for (int c = 0; c < 10; ++c) v[c] = p[c] ? *(const s8v*)(p[c]) : sz;

  for (int k0 = 0; k0 < D_MODEL; k0 += 32) {
#pragma unroll
    for (int c = 0; c < 10; ++c)
      *(s8v*)(lds + (size_t)(tid + 256 * c) * 8) = v[c];
    __syncthreads();
    if (k0 + 32 < D_MODEL) {
      const int kn = k0 + 32;
#pragma unroll
      for (int c = 0; c < 10; ++c) v[c] = p[c] ? *(const s8v*)(p[c] + kn) : sz;
    }
    s8v afh[4], afl[4];
#pragma unroll
    for (int m = 0; m < 4; ++m) {
      afh[m] = *(const s8v*)(lds + ((wmb + m) * 64 + lane) * 8);
      afl[m] = *(const s8v*)(lds + 4096 + ((wmb + m) * 64 + lane) * 8);
    }
#pragma unroll
    for (int n = 0; n < 4; ++n) {
      const int boff = ((wnb + n) * 64 + lane) * 8;
      const s8v bgh = *(const s8v*)(lds + 8192 + boff);
      const s8v bgl = *(const s8v*)(lds + 12288 + boff);
      const s8v buh = *(const s8v*)(lds + 16384 + boff);
#pragma unroll
      for (int m = 0; m < 4; ++m) {
        acc_g[m][n] = __builtin_amdgcn_mfma_f32_16x16x32_bf16(afh[m], bgh, acc_g[m][n], 0, 0, 0);
        acc_g[m][n] = __builtin_amdgcn_mfma_f32_16x16x32_bf16(afh[m], bgl, acc_g[m][n], 0, 0, 0);
        acc_g[m][n] = __builtin_amdgcn_mfma_f32_16x16x32_bf16(afl[m], bgh, acc_g[m][n], 0, 0, 0);
        acc_u[m][n] = __builtin_amdgcn_mfma_f32_16x16x32_bf16(afh[m], buh, acc_u[m][n], 0, 0, 0);
      }
    }
    __syncthreads();
  }

  const int lcol = lane & 15;
  const int lrow = (lane >> 4) * 4;
#pragma unroll
  for (int n = 0; n < 4; ++n) {
    const int col = n0 + (wnb + n) * 16 + lcol;
    const float bgv = bgate[e * HID + col];
    const float buv = bup[e * HID + col];
#pragma unroll
    for (int m = 0; m < 4; ++m) {
#pragma unroll
      for (int i = 0; i < 4; ++i) {
        const int r = (wmb + m) * 16 + lrow + i;
        if (r < rows) {
          const float g = acc_g[m][n][i] + bgv;
          const float u = acc_u[m][n][i] + buv;
          hbuf[(size_t)(row0 + r) * HID + col] = f2bf(g > 1.0f ? u : 0.0f);
          if (fabsf(g - 1.0f) < BAND) {
            const unsigned idx = atomicAdd((unsigned*)(meta + 1), 1u);
            if (idx < FLAGCAP) flags[idx] = ((unsigned)(row0 + r) << 16) | (unsigned)col;
          }
        }
      }
    }
  }
}

// ===== stage B (bf16 pre-converted path): y = h @ W_down =====
__launch_bounds__(256, 2)
__global__ void k_stage_b_bf(const unsigned short* __restrict__ hbuf,
                             const unsigned short* __restrict__ wdh,
                             const int4* __restrict__ tile_tab,
                             const int* __restrict__ meta,
                             float* __restrict__ ybuf) {
  const int NB = D_MODEL / 128;  // 8
  const int tile_id = blockIdx.x / NB;
  const int bn = blockIdx.x % NB;
  if (tile_id >= meta[0]) return;
  const int4 tt = tile_tab[tile_id];
  const int e = tt.x, row0 = tt.y, rows = tt.z;
  const int n0 = bn * 128;

  __shared__ __align__(16) unsigned short lds[2 * 8192];

  const int tid = threadIdx.x;
  const int lane = tid & 63;
  const int wid = tid >> 6;
  const int wmb = (wid >> 1) * 4;
  const int wnb = (wid & 1) * 4;

  const unsigned short* p[8];
#pragma unroll
  for (int c = 0; c < 8; ++c) {
    const int idx = tid + 256 * c;
    const int arr = idx >> 10;
    const int q = idx & 1023;
    const int rn = ((q >> 7) << 4) + (q & 15);
    const int j = (q & 127) >> 4;
    if (arr == 0) {
      p[c] = (rn < rows) ? (hbuf + (size_t)(row0 + rn) * HID + 8 * j) : nullptr;
    } else {
      p[c] = wdh + ((size_t)e * D_MODEL + n0 + rn) * HID + 8 * j;
    }
  }

  const f4v fz = {0.f, 0.f, 0.f, 0.f};
  f4v acc[4][4];
#pragma unroll
  for (int m = 0; m < 4; ++m)
#pragma unroll
    for (int n = 0; n < 4; ++n) acc[m][n] = fz;
  const s8v sz = {0, 0, 0, 0, 0, 0, 0, 0};

  s8v v[8];
#pragma unroll
  for (int c = 0; c < 8; ++c) v[c] = p[c] ? *(const s8v*)(p[c]) : sz;

  for (int k0 = 0; k0 < HID; k0 += 64) {
#pragma unroll
    for (int c = 0; c < 8; ++c)
      *(s8v*)(lds + (size_t)(tid + 256 * c) * 8) = v[c];
    __syncthreads();
    if (k0 + 64 < HID) {
      const int kn = k0 + 64;
#pragma unroll
      for (int c = 0; c < 8; ++c) v[c] = p[c] ? *(const s8v*)(p[c] + kn) : sz;
    }
#pragma unroll
    for (int kk = 0; kk < 2; ++kk) {
      s8v af[4];
#pragma unroll
      for (int m = 0; m < 4; ++m)
        af[m] = *(const s8v*)(lds + ((wmb + m) * 128 + kk * 64 + lane) * 8);
#pragma unroll
      for (int n = 0; n < 4; ++n) {
        const s8v bv = *(const s8v*)(lds + 8192 + ((wnb + n) * 128 + kk * 64 + lane) * 8);
#pragma unroll
        for (int m = 0; m < 4; ++m)
          acc[m][n] = __builtin_amdgcn_mfma_f32_16x16x32_bf16(af[m], bv, acc[m][n], 0, 0, 0);
      }
    }
    __syncthreads();
  }

  const int lcol = lane & 15;
  const int lrow = (lane >> 4) * 4;
#pragma unroll
  for (int m = 0; m < 4; ++m)
#pragma unroll
    for (int i = 0; i < 4; ++i) {
      const int r = (wmb + m) * 16 + lrow + i;
      if (r < rows) {
#pragma unroll
        for (int n = 0; n < 4; ++n) {
          const int col = n0 + (wnb + n) * 16 + lcol;
          ybuf[(size_t)(row0 + r) * D_MODEL + col] = acc[m][n][i];
        }
      }
    }
}

// ===== round-4 fallback GEMMs (on-the-fly f32->bf16 conversion) =====
__launch_bounds__(256, 2)
__global__ void k_stage_a_f32(const unsigned short* __restrict__ xh,
                              const unsigned short* __restrict__ xl,
                              const float* __restrict__ Wgate, const float* __restrict__ bgate,
                              const float* __restrict__ Wup, const float* __restrict__ bup,
                              const int* __restrict__ pair_token,
                              const int4* __restrict__ tile_tab,
                              int* meta,
                              unsigned short* __restrict__ hbuf,
                              unsigned int* __restrict__ flags) {
  const int NB = HID / 128;
  const int tile_id = blockIdx.x / NB;
  const int bn = blockIdx.x % NB;
  if (tile_id >= meta[0]) return;
  const int4 tt = tile_tab[tile_id];
  const int e = tt.x, row0 = tt.y, rows = tt.z;
  const int n0 = bn * 128;

  __shared__ __align__(16) unsigned short la_h[128 * 32];
  __shared__ __align__(16) unsigned short la_l[128 * 32];
  __shared__ __align__(16) unsigned short lb_gh[128 * 32];
  __shared__ __align__(16) unsigned short lb_gl[128 * 32];
  __shared__ __align__(16) unsigned short lb_uh[128 * 32];

  const int tid = threadIdx.x;
  const int lane = tid & 63;
  const int wid = tid >> 6;
  const int wmb = (wid >> 1) * 4;
  const int wnb = (wid & 1) * 4;

  const int amat = tid >> 7;
  const unsigned short* const asrc = amat ? xl : xh;
  unsigned short* const albase = amat ? la_l : la_h;
  const unsigned short* ap[4];
#pragma unroll
  for (int c = 0; c < 4; ++c) {
    const int q = (tid & 127) + 128 * c;
    const int r = ((q >> 6) << 4) + (q & 15);
    const int j = (q & 63) >> 4;
    if (r < rows) {
      const int tok = pair_token[row0 + r];
      ap[c] = asrc + (size_t)tok * D_MODEL + 8 * j;
    } else ap[c] = nullptr;
  }

  const int bsel = tid >> 7;
  const float* const bcolbase = (bsel ? Wup : Wgate) + (size_t)e * D_MODEL * HID + n0;
  const float* bp[4];
  int bj[4];
#pragma unroll
  for (int c = 0; c < 4; ++c) {
    const int q = (tid & 127) + 128 * c;
    const int n = ((q >> 6) << 4) + (q & 15);
    bj[c] = (q & 63) >> 4;
    bp[c] = bcolbase + n;
  }

  const f4v fz = {0.f, 0.f, 0.f, 0.f};
  f4v acc_g[4][4], acc_u[4][4];
#pragma unroll
  for (int m = 0; m < 4; ++m)
#pragma unroll
    for (int n = 0; n < 4; ++n) { acc_g[m][n] = fz; acc_u[m][n] = fz; }

  const s8v sz = {0, 0, 0, 0, 0, 0, 0, 0};

  for (int k0 = 0; k0 < D_MODEL; k0 += 32) {
#pragma unroll
    for (int c = 0; c < 4; ++c) {
      const int q = (tid & 127) + 128 * c;
      s8v v = sz;
      if (ap[c]) v = *(const s8v*)(ap[c] + k0);
      *(s8v*)(albase + q * 8) = v;
    }
    if (bsel == 0) {
#pragma unroll
      for (int c = 0; c < 4; ++c) {
        const int q = (tid & 127) + 128 * c;
        s8v vh, vl;
#pragma unroll
        for (int i = 0; i < 8; ++i) {
          const float g = bp[c][(size_t)(k0 + 8 * bj[c] + i) * HID];
          const unsigned short hh = f2bf(g);
          vh[i] = (short)hh;
          vl[i] = (short)f2bf(g - bf2f(hh));
        }
        *(s8v*)(lb_gh + q * 8) = vh;
        *(s8v*)(lb_gl + q * 8) = vl;
      }
    } else {
#pragma unroll
      for (int c = 0; c < 4; ++c) {
        const int q = (tid & 127) + 128 * c;
        s8v vu;
#pragma unroll
        for (int i = 0; i < 8; ++i)
          vu[i] = (short)f2bf(bp[c][(size_t)(k0 + 8 * bj[c] + i) * HID]);
        *(s8v*)(lb_uh + q * 8) = vu;
      }
    }
    __syncthreads();
    s8v afh[4], afl[4];
#pragma unroll
    for (int m = 0; m < 4; ++m) {
      afh[m] = *(const s8v*)(la_h + ((wmb + m) * 64 + lane) * 8);
      afl[m] = *(const s8v*)(la_l + ((wmb + m) * 64 + lane) * 8);
    }
#pragma unroll
    for (int n = 0; n < 4; ++n) {
      const int boff = ((wnb + n) * 64 + lane) * 8;
      const s8v bgh = *(const s8v*)(lb_gh + boff);
      const s8v bgl = *(const s8v*)(lb_gl + boff);
      const s8v buh = *(const s8v*)(lb_uh + boff);
#pragma unroll
      for (int m = 0; m < 4; ++m) {
        acc_g[m][n] = __builtin_amdgcn_mfma_f32_16x16x32_bf16(afh[m], bgh, acc_g[m][n], 0, 0, 0);
        acc_g[m][n] = __builtin_amdgcn_mfma_f32_16x16x32_bf16(afh[m], bgl, acc_g[m][n], 0, 0, 0);
        acc_g[m][n] = __builtin_amdgcn_mfma_f32_16x16x32_bf16(afl[m], bgh, acc_g[m][n], 0, 0, 0);
        acc_u[m][n] = __builtin_amdgcn_mfma_f32_16x16x32_bf16(afh[m], buh, acc_u[m][n], 0, 0, 0);
      }
    }
    __syncthreads();
  }

  const int lcol = lane & 15;
  const int lrow = (lane >> 4) * 4;
#pragma unroll
  for (int n = 0; n < 4; ++n) {
    const int col = n0 + (wnb + n) * 16 + lcol;
    const float bgv = bgate[e * HID + col];
    const float buv = bup[e * HID + col];
#pragma unroll
    for (int m = 0; m < 4; ++m) {
#pragma unroll
      for (int i = 0; i < 4; ++i) {
        const int r = (wmb + m) * 16 + lrow + i;
        if (r < rows) {
          const float g = acc_g[m][n][i] + bgv;
          const float u = acc_u[m][n][i] + buv;
          hbuf[(size_t)(row0 + r) * HID + col] = f2bf(g > 1.0f ? u : 0.0f);
          if (fabsf(g - 1.0f) < BAND) {
            const unsigned idx = atomicAdd((unsigned*)(meta + 1), 1u);
            if (idx < FLAGCAP) flags[idx] = ((unsigned)(row0 + r) << 16) | (unsigned)col;
          }
        }
      }
    }
  }
}

__launch_bounds__(256, 2)
__global__ void k_stage_b_f32(const unsigned short* __restrict__ hbuf,
                              const float* __restrict__ Wdown,
                              const int4* __restrict__ tile_tab,
                              const int* __restrict__ meta,
                              float* __restrict__ ybuf) {
  const int NB = D_MODEL / 128;
  const int tile_id = blockIdx.x / NB;
  const int bn = blockIdx.x % NB;
  if (tile_id >= meta[0]) return;
  const int4 tt = tile_tab[tile_id];
  const int e = tt.x, row0 = tt.y, rows = tt.z;
  const int n0 = bn * 128;

  __shared__ __align__(16) unsigned short la[128 * 64];
  __shared__ __align__(16) unsigned short lb[128 * 64];

  const int tid = threadIdx.x;
  const int lane = tid & 63;
  const int wid = tid >> 6;
  const int wmb = (wid >> 1) * 4;
  const int wnb = (wid & 1) * 4;

  const unsigned short* ap[4];
#pragma unroll
  for (int c = 0; c < 4; ++c) {
    const int q = tid + 256 * c;
    const int r = ((q >> 7) << 4) + (q & 15);
    const int j = (q & 127) >> 4;
    ap[c] = (r < rows) ? (hbuf + (size_t)(row0 + r) * HID + 8 * j) : nullptr;
  }
  const float* const bcolbase = Wdown + (size_t)e * HID * D_MODEL + n0;
  const float* bp[4];
  int bj[4];
#pragma unroll
  for (int c = 0; c < 4; ++c) {
    const int q = tid + 256 * c;
    const int n = ((q >> 7) << 4) + (q & 15);
    bj[c] = (q & 127) >> 4;
    bp[c] = bcolbase + n;
  }

  const f4v fz = {0.f, 0.f, 0.f, 0.f};
  f4v acc[4][4];
#pragma unroll
  for (int m = 0; m < 4; ++m)
#pragma unroll
    for (int n = 0; n < 4; ++n) acc[m][n] = fz;
  const s8v sz = {0, 0, 0, 0, 0, 0, 0, 0};

  for (int k0 = 0; k0 < HID; k0 += 64) {
#pragma unroll
    for (int c = 0; c < 4; ++c) {
      const int q = tid + 256 * c;
      s8v v = sz;
      if (ap[c]) v = *(const s8v*)(ap[c] + k0);
      *(s8v*)(la + q * 8) = v;
    }
#pragma unroll
    for (int c = 0; c < 4; ++c) {
      const int q = tid + 256 * c;
      s8v v;
#pragma unroll
      for (int i = 0; i < 8; ++i)
        v[i] = (short)f2bf(bp[c][(size_t)(k0 + 8 * bj[c] + i) * D_MODEL]);
      *(s8v*)(lb + q * 8) = v;
    }
    __syncthreads();
#pragma unroll
    for (int kk = 0; kk < 2; ++kk) {
      s8v af[4];
#pragma unroll
      for (int m = 0; m < 4; ++m)
        af[m] = *(const s8v*)(la + ((wmb + m) * 128 + kk * 64 + lane) * 8);
#pragma unroll
      for (int n = 0; n < 4; ++n) {
        const s8v bv = *(const s8v*)(lb + ((wnb + n) * 128 + kk * 64 + lane) * 8);
#pragma unroll
        for (int m = 0; m < 4; ++m)
          acc[m][n] = __builtin_amdgcn_mfma_f32_16x16x32_bf16(af[m], bv, acc[m][n], 0, 0, 0);
      }
    }
    __syncthreads();
  }

  const int lcol = lane & 15;
  const int lrow = (lane >> 4) * 4;
#pragma unroll
  for (int m = 0; m < 4; ++m)
#pragma unroll
    for (int i = 0; i < 4; ++i) {
      const int r = (wmb + m) * 16 + lrow + i;
      if (r < rows) {
#pragma unroll
        for (int n = 0; n < 4; ++n) {
          const int col = n0 + (wnb + n) * 16 + lcol;
          ybuf[(size_t)(row0 + r) * D_MODEL + col] = acc[m][n][i];
        }
      }
    }
}

// ---- patch: wave-per-flag f64 recompute; inner band -> exact np emulation ----
__global__ void k_patch(const float* __restrict__ x,
                        const float* __restrict__ Wgate, const float* __restrict__ bgate,
                        const float* __restrict__ Wup, const float* __restrict__ bup,
                        const int* __restrict__ pair_token, const int* __restrict__ pair_expert,
                        const int* __restrict__ meta, const unsigned* __restrict__ flags,
                        unsigned short* __restrict__ hbuf) {
  const int nw = (gridDim.x * blockDim.x) >> 6;
  const int w = (blockIdx.x * blockDim.x + threadIdx.x) >> 6;
  const int lane = threadIdx.x & 63;
  int n = meta[1];
  if (n > FLAGCAP) n = FLAGCAP;
  for (int f = w; f < n; f += nw) {
    const unsigned fl = flags[f];
    const int row = (int)(fl >> 16);
    const int col = (int)(fl & 0xFFFFu);
    const int tok = pair_token[row];
    const int e = pair_expert[row];
    const float* xr = x + (size_t)tok * D_MODEL;
    const float* wg = Wgate + (size_t)e * D_MODEL * HID + col;
    const float* wu = Wup + (size_t)e * D_MODEL * HID + col;
    double g = 0.0, u = 0.0;
#pragma unroll
    for (int i = 0; i < D_MODEL / 64; ++i) {
      const int d = lane + 64 * i;
      const double xv = (double)xr[d];
      g = fma(xv, (double)wg[(size_t)d * HID], g);
      u = fma(xv, (double)wu[(size_t)d * HID], u);
    }
#pragma unroll
    for (int s = 32; s > 0; s >>= 1) { g += __shfl_down(g, s); u += __shfl_down(u, s); }
    if (lane == 0) {
      g += (double)bgate[e * HID + col];
      u += (double)bup[e * HID + col];
      bool spike;
      if (fabs(g - 1.0) < INNER)
        spike = np_spike(xr, wg, HID, bgate[e * HID + col]);
      else
        spike = g > 1.0;
      hbuf[(size_t)row * HID + col] = f2bf(spike ? (float)u : 0.0f);
    }
  }
}

// ---------------- combine: out = w0*(y0+bd0) + w1*(y1+bd1) ----------------
__global__ void k_combine(const float* __restrict__ ybuf, const float* __restrict__ bdown,
                          const int* __restrict__ tok_pair, const int* __restrict__ top_e,
                          const float* __restrict__ top_w, float* __restrict__ out) {
  const int t = blockIdx.x;
  const int c = threadIdx.x;
  const int p0 = tok_pair[2 * t], p1 = tok_pair[2 * t + 1];
  const float w0 = top_w[2 * t], w1 = top_w[2 * t + 1];
  const int e0 = top_e[2 * t], e1 = top_e[2 * t + 1];
  const float4 y0 = ((const float4*)(ybuf + (size_t)p0 * D_MODEL))[c];
  const float4 y1 = ((const float4*)(ybuf + (size_t)p1 * D_MODEL))[c];
  const float4 b0 = ((const float4*)(bdown + (size_t)e0 * D_MODEL))[c];
  const float4 b1 = ((const float4*)(bdown + (size_t)e1 * D_MODEL))[c];
  float4 o;
  o.x = w0 * (y0.x + b0.x) + w1 * (y1.x + b1.x);
  o.y = w0 * (y0.y + b0.y) + w1 * (y1.y + b1.y);
  o.z = w0 * (y0.z + b0.z) + w1 * (y1.z + b1.z);
  o.w = w0 * (y0.w + b0.w) + w1 * (y1.w + b1.w);
  ((float4*)(out + (size_t)t * D_MODEL))[c] = o;
}

extern "C" void kernel_launch(void* const* d_in, const int* in_sizes, int n_in,
                              void* d_out, int out_size, void* d_ws, size_t ws_size,
                              hipStream_t stream) {
  const float* x     = (const float*)d_in[0];
  const float* Wg    = (const float*)d_in[1];
  const float* bg    = (const float*)d_in[2];
  const float* Wgate = (const float*)d_in[3];
  const float* bgate = (const float*)d_in[4];
  const float* Wup   = (const float*)d_in[5];
  const float* bup   = (const float*)d_in[6];
  const float* Wdown = (const float*)d_in[7];
  const float* bdown = (const float*)d_in[8];
  float* out = (float*)d_out;

  char* ws = (char*)d_ws;
  unsigned short* xh   = (unsigned short*)(ws + 0);
  unsigned short* xl   = (unsigned short*)(ws + 4194304);
  unsigned short* hbuf = (unsigned short*)(ws + 8388608);
  float* ybuf          = (float*)(ws + 31457280);
  int* top_e           = (int*)(ws + 48234496);
  float* top_w         = (float*)(ws + 48250880);
  int* pair_token      = (int*)(ws + 48267264);
  int* pair_expert     = (int*)(ws + 48283648);
  int* tok_pair        = (int*)(ws + 48300032);
  int4* tile_tab       = (int4*)(ws + 48316416);
  int* meta            = (int*)(ws + 48317184);
  unsigned* flags      = (unsigned*)(ws + 48317440);
  // bf16 transposed weight panels (big-ws path)
  unsigned short* wgh  = (unsigned short*)(ws + 48579584);
  unsigned short* wgl  = (unsigned short*)(ws + 94716928);
  unsigned short* wuh  = (unsigned short*)(ws + 140854272);
  unsigned short* wdh  = (unsigned short*)(ws + 186991616);
  const bool big = ws_size >= 233128960ull;

  k_convx<<<dim3(NTOK * D_MODEL / 4 / 256), dim3(256), 0, stream>>>(x, xh, xl);
  if (big) {
    k_convw<<<dim3(44 * 16, NEXP), dim3(256), 0, stream>>>(Wgate, wgh, wgl, D_MODEL, HID);
    k_convw<<<dim3(44 * 16, NEXP), dim3(256), 0, stream>>>(Wup, wuh, nullptr, D_MODEL, HID);
    k_convw<<<dim3(16 * 44, NEXP), dim3(256), 0, stream>>>(Wdown, wdh, nullptr, HID, D_MODEL);
  }
  k_router<<<dim3(NTOK / 4), dim3(256), 0, stream>>>(x, Wg, bg, top_e, top_w);
  k_group<<<dim3(1), dim3(256), 0, stream>>>(top_e, pair_token, pair_expert, tok_pair,
                                             tile_tab, meta);
  if (big) {
    k_stage_a_bf<<<dim3(MAXTILES * (HID / 128)), dim3(256), 0, stream>>>(
        xh, xl, wgh, wgl, wuh, bgate, bup, pair_token, tile_tab, meta, hbuf, flags);
  } else {
    k_stage_a_f32<<<dim3(MAXTILES * (HID / 128)), dim3(256), 0, stream>>>(
        xh, xl, Wgate, bgate, Wup, bup, pair_token, tile_tab, meta, hbuf, flags);
  }
  k_patch<<<dim3(512), dim3(256), 0, stream>>>(x, Wgate, bgate, Wup, bup, pair_token,
                                               pair_expert, meta, flags, hbuf);
  if (big) {
    k_stage_b_bf<<<dim3(MAXTILES * (D_MODEL / 128)), dim3(256), 0, stream>>>(
        hbuf, wdh, tile_tab, meta, ybuf);
  } else {
    k_stage_b_f32<<<dim3(MAXTILES * (D_MODEL / 128)), dim3(256), 0, stream>>>(
        hbuf, Wdown, tile_tab, meta, ybuf);
  }
  k_combine<<<dim3(NTOK), dim3(256), 0, stream>>>(ybuf, bdown, tok_pair, top_e, top_w, out);
}

// Round 6
// 509.694 us; speedup vs baseline: 2.4864x; 1.0047x over previous
//
#include <hip/hip_runtime.h>

// SpikingMoEFFN: top-2-of-8 spiking router + per-expert SpikingSwiGLU.
// Grouped-GEMM implementation. Spike decisions emulate the np reference's
// f32 BLAS accumulation (sgemm KC=384 panels; verified round 3) via bf16x3
// MFMA screen + f64/exact-emulation patch.
// Round 6: stage GEMM operands with __builtin_amdgcn_global_load_lds
// (width=16, linear fragment-major LDS dest) instead of reg round-trip.

#define D_MODEL 1024
#define HID     2816
#define NEXP    8
#define NTOK    2048
#define NPAIR   4096
#define TM      128
#define MAXTILES 40
#define FLAGCAP  65536
#define KC      384
#define BAND    3e-4f
#define INNER   2e-5

typedef short s8v __attribute__((ext_vector_type(8)));
typedef float f4v __attribute__((ext_vector_type(4)));

__device__ __forceinline__ unsigned short f2bf(float f) {
  unsigned u = __float_as_uint(f);
  u += 0x7FFFu + ((u >> 16) & 1u);   // RTNE
  return (unsigned short)(u >> 16);
}
__device__ __forceinline__ float bf2f(unsigned short s) {
  return __uint_as_float(((unsigned)s) << 16);
}

// async global->LDS, 16B per lane; LDS dest = wave-uniform base + lane*16
__device__ __forceinline__ void gld16(const unsigned short* g, unsigned short* l) {
  __builtin_amdgcn_global_load_lds(
      (const __attribute__((address_space(1))) void*)g,
      (__attribute__((address_space(3))) void*)l, 16, 0, 0);
}

// Exact np-f32 gate emulation: seq FMA within KC=384 panels, panels added
// in order, then + bias.
__device__ __forceinline__ bool np_spike(const float* __restrict__ xr,
                                         const float* __restrict__ wcol,
                                         size_t stride, float bias) {
  float g = 0.0f;
  for (int p0 = 0; p0 < D_MODEL; p0 += KC) {
    const int pe = min(p0 + KC, D_MODEL);
    float s = 0.0f;
    for (int d = p0; d < pe; ++d)
      s = fmaf(xr[d], wcol[(size_t)d * stride], s);
    g += s;
  }
  g += bias;
  return g > 1.0f;
}

// ---------------- x -> bf16 hi/lo split ----------------
__global__ void k_convx(const float* __restrict__ x, unsigned short* __restrict__ xh,
                        unsigned short* __restrict__ xl) {
  const int i = blockIdx.x * 256 + threadIdx.x;
  const float4 v = ((const float4*)x)[i];
  ushort4 h, l;
  h.x = f2bf(v.x); l.x = f2bf(v.x - bf2f(h.x));
  h.y = f2bf(v.y); l.y = f2bf(v.y - bf2f(h.y));
  h.z = f2bf(v.z); l.z = f2bf(v.z - bf2f(h.z));
  h.w = f2bf(v.w); l.w = f2bf(v.w - bf2f(h.w));
  ((ushort4*)xh)[i] = h;
  ((ushort4*)xl)[i] = l;
}

// ------- weight transpose+convert: in [R][C] f32 -> out [C][R] bf16 (hi[,lo]) ---
__global__ void k_convw(const float* __restrict__ in, unsigned short* __restrict__ hi,
                        unsigned short* __restrict__ lo, int R, int C) {
  const int e = blockIdx.y;
  const int ntx = C >> 6;
  const int tx = blockIdx.x % ntx;
  const int ty = blockIdx.x / ntx;
  const float* src = in + (size_t)e * R * C;
  const size_t obase = (size_t)e * R * C;
  __shared__ float t[64][65];
  const int tid = threadIdx.x;
#pragma unroll
  for (int it = 0; it < 4; ++it) {
    const int r = it * 16 + (tid >> 4);
    const float4 v = *(const float4*)(src + (size_t)(ty * 64 + r) * C + tx * 64 + (tid & 15) * 4);
    t[r][(tid & 15) * 4 + 0] = v.x;
    t[r][(tid & 15) * 4 + 1] = v.y;
    t[r][(tid & 15) * 4 + 2] = v.z;
    t[r][(tid & 15) * 4 + 3] = v.w;
  }
  __syncthreads();
#pragma unroll
  for (int it = 0; it < 2; ++it) {
    const int c = it * 32 + (tid >> 3);
    const int d0 = (tid & 7) * 8;
    s8v vh, vl;
#pragma unroll
    for (int i = 0; i < 8; ++i) {
      const float f = t[d0 + i][c];
      const unsigned short h = f2bf(f);
      vh[i] = (short)h;
      vl[i] = (short)f2bf(f - bf2f(h));
    }
    const size_t o = obase + (size_t)(tx * 64 + c) * R + ty * 64 + d0;
    *(s8v*)(hi + o) = vh;
    if (lo) *(s8v*)(lo + o) = vl;
  }
}

// ------- router: wave-per-token f64 logits; inner band -> exact np emu -------
__global__ void k_router(const float* __restrict__ x, const float* __restrict__ Wg,
                         const float* __restrict__ bg, int* __restrict__ top_e,
                         float* __restrict__ top_w) {
  const int t = (blockIdx.x * blockDim.x + threadIdx.x) >> 6;
  const int lane = threadIdx.x & 63;
  if (t >= NTOK) return;
  const float* xr = x + (size_t)t * D_MODEL;
  double acc[NEXP];
#pragma unroll
  for (int e = 0; e < NEXP; ++e) acc[e] = 0.0;
#pragma unroll
  for (int i = 0; i < D_MODEL / 64; ++i) {
    const int d = lane + 64 * i;
    const double xv = (double)xr[d];
    const float4 w0 = *(const float4*)(Wg + d * NEXP);
    const float4 w1 = *(const float4*)(Wg + d * NEXP + 4);
    acc[0] = fma(xv, (double)w0.x, acc[0]);
    acc[1] = fma(xv, (double)w0.y, acc[1]);
    acc[2] = fma(xv, (double)w0.z, acc[2]);
    acc[3] = fma(xv, (double)w0.w, acc[3]);
    acc[4] = fma(xv, (double)w1.x, acc[4]);
    acc[5] = fma(xv, (double)w1.y, acc[5]);
    acc[6] = fma(xv, (double)w1.z, acc[6]);
    acc[7] = fma(xv, (double)w1.w, acc[7]);
  }
#pragma unroll
  for (int e = 0; e < NEXP; ++e) {
#pragma unroll
    for (int s = 32; s > 0; s >>= 1) acc[e] += __shfl_down(acc[e], s);
  }
  if (lane == 0) {
    bool sp[NEXP];
#pragma unroll
    for (int e = 0; e < NEXP; ++e) {
      const double l = acc[e] + (double)bg[e];
      if (fabs(l - 1.0) < INNER)
        sp[e] = np_spike(xr, Wg + e, NEXP, bg[e]);
      else
        sp[e] = l > 1.0;
    }
    int e0 = -1, e1 = -1;
    for (int e = 0; e < NEXP; ++e) if (sp[e])  { if (e0 < 0) e0 = e; else if (e1 < 0) e1 = e; }
    for (int e = 0; e < NEXP; ++e) if (!sp[e]) { if (e0 < 0) e0 = e; else if (e1 < 0) e1 = e; }
    float w0v, w1v;
    if (sp[e0] == sp[e1]) { w0v = 0.5f; w1v = 0.5f; }
    else { w0v = 0.7310585786300049f; w1v = 0.2689414213699951f; }  // softmax([1,0])
    top_e[2 * t] = e0; top_e[2 * t + 1] = e1;
    top_w[2 * t] = w0v; top_w[2 * t + 1] = w1v;
  }
}

// ---------------- group pairs by expert, build tile table ----------------
__global__ void k_group(const int* __restrict__ top_e,
                        int* __restrict__ pair_token, int* __restrict__ pair_expert,
                        int* __restrict__ tok_pair, int4* __restrict__ tile_tab,
                        int* __restrict__ meta) {
  __shared__ int cnt[NEXP], off[NEXP + 1], fill[NEXP];
  const int tid = threadIdx.x;
  if (tid < NEXP) { cnt[tid] = 0; fill[tid] = 0; }
  __syncthreads();
  for (int i = tid; i < NPAIR; i += 256) atomicAdd(&cnt[top_e[i]], 1);
  __syncthreads();
  if (tid == 0) {
    off[0] = 0;
    for (int e = 0; e < NEXP; ++e) off[e + 1] = off[e] + cnt[e];
    int nt = 0;
    for (int e = 0; e < NEXP; ++e)
      for (int s = 0; s < cnt[e]; s += TM) {
        tile_tab[nt] = make_int4(e, off[e] + s, min(TM, cnt[e] - s), 0);
        ++nt;
      }
    meta[0] = nt;   // ntiles
    meta[1] = 0;    // flag count
  }
  __syncthreads();
  for (int i = tid; i < NPAIR; i += 256) {
    const int e = top_e[i];
    const int pos = off[e] + atomicAdd(&fill[e], 1);
    pair_token[pos] = i >> 1;
    pair_expert[pos] = e;
    tok_pair[i] = pos;
  }
}

// ===== stage A: h = spike(x@Wg+bg) * (x@Wu+bu), glds staging =====
__launch_bounds__(256, 2)
__global__ void k_stage_a_bf(const unsigned short* __restrict__ xh,
                             const unsigned short* __restrict__ xl,
                             const unsigned short* __restrict__ wgh,
                             const unsigned short* __restrict__ wgl,
                             const unsigned short* __restrict__ wuh,
                             const float* __restrict__ bgate, const float* __restrict__ bup,
                             const int* __restrict__ pair_token,
                             const int4* __restrict__ tile_tab,
                             int* meta,
                             unsigned short* __restrict__ hbuf,
                             unsigned int* __restrict__ flags) {
  const int NB = HID / 128;  // 22
  const int tile_id = blockIdx.x / NB;
  const int bn = blockIdx.x % NB;
  if (tile_id >= meta[0]) return;
  const int4 tt = tile_tab[tile_id];
  const int e = tt.x, row0 = tt.y, rows = tt.z;
  const int n0 = bn * 128;

  __shared__ __align__(16) unsigned short lds[5 * 4096];

  const int tid = threadIdx.x;
  const int lane = tid & 63;
  const int wid = tid >> 6;
  const int wmb = (wid >> 1) * 4;
  const int wnb = (wid & 1) * 4;

  const unsigned short* p[10];
#pragma unroll
  for (int c = 0; c < 10; ++c) {
    const int idx = tid + 256 * c;
    const int arr = idx >> 9;
    const int q = idx & 511;
    const int rn = ((q >> 6) << 4) + (q & 15);
    const int j = (q & 63) >> 4;
    if (arr < 2) {
      if (rn < rows) {
        const int tok = pair_token[row0 + rn];
        p[c] = (arr ? xl : xh) + (size_t)tok * D_MODEL + 8 * j;
      } else p[c] = xh;  // dummy valid address; rows >= `rows` never stored
    } else {
      const unsigned short* base = (arr == 2) ? wgh : (arr == 3) ? wgl : wuh;
      p[c] = base + ((size_t)e * HID + n0 + rn) * D_MODEL + 8 * j;
    }
  }

  const f4v fz = {0.f, 0.f, 0.f, 0.f};
  f4v acc_g[4][4], acc_u[4][4];
#pragma unroll
  for (int m = 0; m < 4; ++m)
#pragma unroll
    for (int n = 0; n < 4; ++n) { acc_g[m][n] = fz; acc_u[m][n] = fz; }

  for (int k0 = 0; k0 < D_MODEL; k0 += 32) {
#pragma unroll
    for (int c = 0; c < 10; ++c)
      gld16(p[c] + k0, lds + (((c << 8) + (tid & 192)) << 3));
    __syncthreads();   // vmcnt(0) drain + barrier
    s8v afh[4], afl[4];
#pragma unroll
    for (int m = 0; m < 4; ++m) {
      afh[m] = *(const s8v*)(lds + ((wmb + m) * 64 + lane) * 8);
      afl[m] = *(const s8v*)(lds + 4096 + ((wmb + m) * 64 + lane) * 8);
    }
#pragma unroll
    for (int n = 0; n < 4; ++n) {
      const int boff = ((wnb + n) * 64 + lane) * 8;
      const s8v bgh = *(const s8v*)(lds + 8192 + boff);
      const s8v bgl = *(const s8v*)(lds + 12288 + boff);
      const s8v buh = *(const s8v*)(lds + 16384 + boff);
#pragma unroll
      for (int m = 0; m < 4; ++m) {
        acc_g[m][n] = __builtin_amdgcn_mfma_f32_16x16x32_bf16(afh[m], bgh, acc_g[m][n], 0, 0, 0);
        acc_g[m][n] = __builtin_amdgcn_mfma_f32_16x16x32_bf16(afh[m], bgl, acc_g[m][n], 0, 0, 0);
        acc_g[m][n] = __builtin_amdgcn_mfma_f32_16x16x32_bf16(afl[m], bgh, acc_g[m][n], 0, 0, 0);
        acc_u[m][n] = __builtin_amdgcn_mfma_f32_16x16x32_bf16(afh[m], buh, acc_u[m][n], 0, 0, 0);
      }
    }
    __syncthreads();
  }

  const int lcol = lane & 15;
  const int lrow = (lane >> 4) * 4;
#pragma unroll
  for (int n = 0; n < 4; ++n) {
    const int col = n0 + (wnb + n) * 16 + lcol;
    const float bgv = bgate[e * HID + col];
    const float buv = bup[e * HID + col];
#pragma unroll
    for (int m = 0; m < 4; ++m) {
#pragma unroll
      for (int i = 0; i < 4; ++i) {
        const int r = (wmb + m) * 16 + lrow + i;
        if (r < rows) {
          const float g = acc_g[m][n][i] + bgv;
          const float u = acc_u[m][n][i] + buv;
          hbuf[(size_t)(row0 + r) * HID + col] = f2bf(g > 1.0f ? u : 0.0f);
          if (fabsf(g - 1.0f) < BAND) {
            const unsigned idx = atomicAdd((unsigned*)(meta + 1), 1u);
            if (idx < FLAGCAP) flags[idx] = ((unsigned)(row0 + r) << 16) | (unsigned)col;
          }
        }
      }
    }
  }
}

// ===== stage B: y = h @ W_down, glds staging =====
__launch_bounds__(256, 2)
__global__ void k_stage_b_bf(const unsigned short* __restrict__ hbuf,
                             const unsigned short* __restrict__ wdh,
                             const int4* __restrict__ tile_tab,
                             const int* __restrict__ meta,
                             float* __restrict__ ybuf) {
  const int NB = D_MODEL / 128;  // 8
  const int tile_id = blockIdx.x / NB;
  const int bn = blockIdx.x % NB;
  if (tile_id >= meta[0]) return;
  const int4 tt = tile_tab[tile_id];
  const int e = tt.x, row0 = tt.y, rows = tt.z;
  const int n0 = bn * 128;

  __shared__ __align__(16) unsigned short lds[2 * 8192];

  const int tid = threadIdx.x;
  const int lane = tid & 63;
  const int wid = tid >> 6;
  const int wmb = (wid >> 1) * 4;
  const int wnb = (wid & 1) * 4;

  const unsigned short* p[8];
#pragma unroll
  for (int c = 0; c < 8; ++c) {
    const int idx = tid + 256 * c;
    const int arr = idx >> 10;
    const int q = idx & 1023;
    const int rn = ((q >> 7) << 4) + (q & 15);
    const int j = (q & 127) >> 4;
    if (arr == 0) {
      p[c] = (rn < rows) ? (hbuf + (size_t)(row0 + rn) * HID + 8 * j) : hbuf;
    } else {
      p[c] = wdh + ((size_t)e * D_MODEL + n0 + rn) * HID + 8 * j;
    }
  }

  const f4v fz = {0.f, 0.f, 0.f, 0.f};
  f4v acc[4][4];
#pragma unroll
  for (int m = 0; m < 4; ++m)
#pragma unroll
    for (int n = 0; n < 4; ++n) acc[m][n] = fz;

  for (int k0 = 0; k0 < HID; k0 += 64) {
#pragma unroll
    for (int c = 0; c < 8; ++c)
      gld16(p[c] + k0, lds + (((c << 8) + (tid & 192)) << 3));
    __syncthreads();
#pragma unroll
    for (int kk = 0; kk < 2; ++kk) {
      s8v af[4];
#pragma unroll
      for (int m = 0; m < 4; ++m)
        af[m] = *(const s8v*)(lds + ((wmb + m) * 128 + kk * 64 + lane) * 8);
#pragma unroll
      for (int n = 0; n < 4; ++n) {
        const s8v bv = *(const s8v*)(lds + 8192 + ((wnb + n) * 128 + kk * 64 + lane) * 8);
#pragma unroll
        for (int m = 0; m < 4; ++m)
          acc[m][n] = __builtin_amdgcn_mfma_f32_16x16x32_bf16(af[m], bv, acc[m][n], 0, 0, 0);
      }
    }
    __syncthreads();
  }

  const int lcol = lane & 15;
  const int lrow = (lane >> 4) * 4;
#pragma unroll
  for (int m = 0; m < 4; ++m)
#pragma unroll
    for (int i = 0; i < 4; ++i) {
      const int r = (wmb + m) * 16 + lrow + i;
      if (r < rows) {
#pragma unroll
        for (int n = 0; n < 4; ++n) {
          const int col = n0 + (wnb + n) * 16 + lcol;
          ybuf[(size_t)(row0 + r) * D_MODEL + col] = acc[m][n][i];
        }
      }
    }
}

// ---- patch: wave-per-flag f64 recompute; inner band -> exact np emulation ----
__global__ void k_patch(const float* __restrict__ x,
                        const float* __restrict__ Wgate, const float* __restrict__ bgate,
                        const float* __restrict__ Wup, const float* __restrict__ bup,
                        const int* __restrict__ pair_token, const int* __restrict__ pair_expert,
                        const int* __restrict__ meta, const unsigned* __restrict__ flags,
                        unsigned short* __restrict__ hbuf) {
  const int nw = (gridDim.x * blockDim.x) >> 6;
  const int w = (blockIdx.x * blockDim.x + threadIdx.x) >> 6;
  const int lane = threadIdx.x & 63;
  int n = meta[1];
  if (n > FLAGCAP) n = FLAGCAP;
  for (int f = w; f < n; f += nw) {
    const unsigned fl = flags[f];
    const int row = (int)(fl >> 16);
    const int col = (int)(fl & 0xFFFFu);
    const int tok = pair_token[row];
    const int e = pair_expert[row];
    const float* xr = x + (size_t)tok * D_MODEL;
    const float* wg = Wgate + (size_t)e * D_MODEL * HID + col;
    const float* wu = Wup + (size_t)e * D_MODEL * HID + col;
    double g = 0.0, u = 0.0;
#pragma unroll
    for (int i = 0; i < D_MODEL / 64; ++i) {
      const int d = lane + 64 * i;
      const double xv = (double)xr[d];
      g = fma(xv, (double)wg[(size_t)d * HID], g);
      u = fma(xv, (double)wu[(size_t)d * HID], u);
    }
#pragma unroll
    for (int s = 32; s > 0; s >>= 1) { g += __shfl_down(g, s); u += __shfl_down(u, s); }
    if (lane == 0) {
      g += (double)bgate[e * HID + col];
      u += (double)bup[e * HID + col];
      bool spike;
      if (fabs(g - 1.0) < INNER)
        spike = np_spike(xr, wg, HID, bgate[e * HID + col]);
      else
        spike = g > 1.0;
      hbuf[(size_t)row * HID + col] = f2bf(spike ? (float)u : 0.0f);
    }
  }
}

// ---------------- combine: out = w0*(y0+bd0) + w1*(y1+bd1) ----------------
__global__ void k_combine(const float* __restrict__ ybuf, const float* __restrict__ bdown,
                          const int* __restrict__ tok_pair, const int* __restrict__ top_e,
                          const float* __restrict__ top_w, float* __restrict__ out) {
  const int t = blockIdx.x;
  const int c = threadIdx.x;
  const int p0 = tok_pair[2 * t], p1 = tok_pair[2 * t + 1];
  const float w0 = top_w[2 * t], w1 = top_w[2 * t + 1];
  const int e0 = top_e[2 * t], e1 = top_e[2 * t + 1];
  const float4 y0 = ((const float4*)(ybuf + (size_t)p0 * D_MODEL))[c];
  const float4 y1 = ((const float4*)(ybuf + (size_t)p1 * D_MODEL))[c];
  const float4 b0 = ((const float4*)(bdown + (size_t)e0 * D_MODEL))[c];
  const float4 b1 = ((const float4*)(bdown + (size_t)e1 * D_MODEL))[c];
  float4 o;
  o.x = w0 * (y0.x + b0.x) + w1 * (y1.x + b1.x);
  o.y = w0 * (y0.y + b0.y) + w1 * (y1.y + b1.y);
  o.z = w0 * (y0.z + b0.z) + w1 * (y1.z + b1.z);
  o.w = w0 * (y0.w + b0.w) + w1 * (y1.w + b1.w);
  ((float4*)(out + (size_t)t * D_MODEL))[c] = o;
}

extern "C" void kernel_launch(void* const* d_in, const int* in_sizes, int n_in,
                              void* d_out, int out_size, void* d_ws, size_t ws_size,
                              hipStream_t stream) {
  const float* x     = (const float*)d_in[0];
  const float* Wg    = (const float*)d_in[1];
  const float* bg    = (const float*)d_in[2];
  const float* Wgate = (const float*)d_in[3];
  const float* bgate = (const float*)d_in[4];
  const float* Wup   = (const float*)d_in[5];
  const float* bup   = (const float*)d_in[6];
  const float* Wdown = (const float*)d_in[7];
  const float* bdown = (const float*)d_in[8];
  float* out = (float*)d_out;

  char* ws = (char*)d_ws;
  unsigned short* xh   = (unsigned short*)(ws + 0);
  unsigned short* xl   = (unsigned short*)(ws + 4194304);
  unsigned short* hbuf = (unsigned short*)(ws + 8388608);
  float* ybuf          = (float*)(ws + 31457280);
  int* top_e           = (int*)(ws + 48234496);
  float* top_w         = (float*)(ws + 48250880);
  int* pair_token      = (int*)(ws + 48267264);
  int* pair_expert     = (int*)(ws + 48283648);
  int* tok_pair        = (int*)(ws + 48300032);
  int4* tile_tab       = (int4*)(ws + 48316416);
  int* meta            = (int*)(ws + 48317184);
  unsigned* flags      = (unsigned*)(ws + 48317440);
  // bf16 transposed weight panels
  unsigned short* wgh  = (unsigned short*)(ws + 48579584);
  unsigned short* wgl  = (unsigned short*)(ws + 94716928);
  unsigned short* wuh  = (unsigned short*)(ws + 140854272);
  unsigned short* wdh  = (unsigned short*)(ws + 186991616);

  k_convx<<<dim3(NTOK * D_MODEL / 4 / 256), dim3(256), 0, stream>>>(x, xh, xl);
  k_convw<<<dim3(44 * 16, NEXP), dim3(256), 0, stream>>>(Wgate, wgh, wgl, D_MODEL, HID);
  k_convw<<<dim3(44 * 16, NEXP), dim3(256), 0, stream>>>(Wup, wuh, nullptr, D_MODEL, HID);
  k_convw<<<dim3(16 * 44, NEXP), dim3(256), 0, stream>>>(Wdown, wdh, nullptr, HID, D_MODEL);
  k_router<<<dim3(NTOK / 4), dim3(256), 0, stream>>>(x, Wg, bg, top_e, top_w);
  k_group<<<dim3(1), dim3(256), 0, stream>>>(top_e, pair_token, pair_expert, tok_pair,
                                             tile_tab, meta);
  k_stage_a_bf<<<dim3(MAXTILES * (HID / 128)), dim3(256), 0, stream>>>(
      xh, xl, wgh, wgl, wuh, bgate, bup, pair_token, tile_tab, meta, hbuf, flags);
  k_patch<<<dim3(512), dim3(256), 0, stream>>>(x, Wgate, bgate, Wup, bup, pair_token,
                                               pair_expert, meta, flags, hbuf);
  k_stage_b_bf<<<dim3(MAXTILES * (D_MODEL / 128)), dim3(256), 0, stream>>>(
      hbuf, wdh, tile_tab, meta, ybuf);
  k_combine<<<dim3(NTOK), dim3(256), 0, stream>>>(ybuf, bdown, tok_pair, top_e, top_w, out);
}